// Round 5
// baseline (6320.589 us; speedup 1.0000x reference)
//
#include <hip/hip_runtime.h>
#include <hip/hip_bf16.h>
#include <cstdint>
#include <cstddef>

#define TOK 16384
#define Hh  1024
#define F2  2048

// ---- per-token router logits: one thread per token ----
__global__ void k_router_t(const float* __restrict__ x, const float* __restrict__ vol,
                           const float* __restrict__ risk, const float* __restrict__ clsb,
                           const float* __restrict__ vw, const float* __restrict__ vb,
                           const float* __restrict__ rw, const float* __restrict__ rb,
                           const float* __restrict__ sw, const float* __restrict__ sb,
                           float* __restrict__ LP, int m0, int Tc) {
  int t = blockIdx.x * blockDim.x + threadIdx.x;   // chunk-local token
  if (t >= Tc) return;
  int s = m0 + t;
  const float4* xr = (const float4*)(x + (size_t)s * Hh);
  float sum = 0.f, sq = 0.f, mx = -1e30f;
  for (int i = 0; i < Hh / 4; ++i) {
    float4 v = xr[i];
    sum += v.x + v.y + v.z + v.w;
    sq  += v.x * v.x + v.y * v.y + v.z * v.z + v.w * v.w;
    mx = fmaxf(mx, fmaxf(fmaxf(v.x, v.y), fmaxf(v.z, v.w)));
  }
  float mean = sum * (1.0f / Hh);
  float var  = sq * (1.0f / Hh) - mean * mean;
  float sd   = sqrtf(fmaxf(var, 0.f));
  float v = vol[s], rk = risk[s];
  #pragma unroll
  for (int d = 0; d < 4; ++d) {
    float acc = clsb[d];
    #pragma unroll
    for (int k = 0; k < 8; ++k)  acc += tanhf(v  * vw[k*4+d] + vb[k*4+d]);
    #pragma unroll
    for (int k = 0; k < 8; ++k)  acc += tanhf(rk * rw[k*4+d] + rb[k*4+d]);
    #pragma unroll
    for (int k = 0; k < 12; ++k)
      acc += tanhf(mean * sw[k*4+d] + sd * sw[48 + k*4+d] + mx * sw[96 + k*4+d] + sb[k*4+d]);
    LP[t * 4 + d] = acc;
  }
}

// ---- GEMM 1 (fp32 VALU): feat = tanh(x @ Wf + fb), A [Tc][1024], Wf [1024][2048] ----
__global__ __launch_bounds__(256)
void k_feat32(const float* __restrict__ A, const float* __restrict__ Bw,
              const float* __restrict__ bias, float* __restrict__ feat) {
  __shared__ float As[16][68];   // [kk][row]
  __shared__ float Bs[16][68];   // [kk][col]
  const int bm = blockIdx.x, bn = blockIdx.y;
  const int tid = threadIdx.x, tx = tid & 15, ty = tid >> 4;
  float acc[4][4] = {};
  for (int k0 = 0; k0 < Hh; k0 += 16) {
    __syncthreads();
    #pragma unroll
    for (int e = 0; e < 4; ++e) {
      int idx = tid + 256 * e;
      int r = idx >> 4, kk = idx & 15;
      As[kk][r] = A[(size_t)(bm * 64 + r) * Hh + k0 + kk];
    }
    #pragma unroll
    for (int e = 0; e < 4; ++e) {
      int idx = tid + 256 * e;
      int kk = idx >> 6, c = idx & 63;
      Bs[kk][c] = Bw[(size_t)(k0 + kk) * F2 + bn * 64 + c];
    }
    __syncthreads();
    #pragma unroll
    for (int kk = 0; kk < 16; ++kk) {
      float4 a4 = *(const float4*)&As[kk][ty * 4];
      float4 b4 = *(const float4*)&Bs[kk][tx * 4];
      float av[4] = {a4.x, a4.y, a4.z, a4.w};
      float bv[4] = {b4.x, b4.y, b4.z, b4.w};
      #pragma unroll
      for (int i = 0; i < 4; ++i)
        #pragma unroll
        for (int j = 0; j < 4; ++j)
          acc[i][j] += av[i] * bv[j];
    }
  }
  #pragma unroll
  for (int i = 0; i < 4; ++i) {
    int gm = bm * 64 + ty * 4 + i;
    #pragma unroll
    for (int j = 0; j < 4; ++j) {
      int gn = bn * 64 + tx * 4 + j;
      feat[(size_t)gm * F2 + gn] = tanhf(acc[i][j] + bias[gn]);
    }
  }
}

// ---- dom logits + softmax, thread-per-token, in-place LP: logits -> P ----
__global__ void k_dom_t(const float* __restrict__ feat, const float* __restrict__ Wc,
                        float* __restrict__ LP, int Tc) {
  int t = blockIdx.x * blockDim.x + threadIdx.x;
  if (t >= Tc) return;
  const float4* fr = (const float4*)(feat + (size_t)t * F2);
  const float4* Wc4 = (const float4*)Wc;    // Wc row f = float4 (d=0..3)
  float a0 = 0, a1 = 0, a2 = 0, a3 = 0;
  for (int f4 = 0; f4 < F2 / 4; ++f4) {
    float4 v = fr[f4];
    float4 w0 = Wc4[f4 * 4 + 0], w1 = Wc4[f4 * 4 + 1];
    float4 w2 = Wc4[f4 * 4 + 2], w3 = Wc4[f4 * 4 + 3];
    a0 += v.x * w0.x + v.y * w1.x + v.z * w2.x + v.w * w3.x;
    a1 += v.x * w0.y + v.y * w1.y + v.z * w2.y + v.w * w3.y;
    a2 += v.x * w0.z + v.y * w1.z + v.z * w2.z + v.w * w3.z;
    a3 += v.x * w0.w + v.y * w1.w + v.z * w2.w + v.w * w3.w;
  }
  float l0 = a0 + LP[t*4+0], l1 = a1 + LP[t*4+1];
  float l2 = a2 + LP[t*4+2], l3 = a3 + LP[t*4+3];
  float m = fmaxf(fmaxf(l0, l1), fmaxf(l2, l3));
  float e0 = expf(l0 - m), e1 = expf(l1 - m), e2 = expf(l2 - m), e3 = expf(l3 - m);
  float inv = 1.f / (e0 + e1 + e2 + e3);
  LP[t*4+0] = e0 * inv; LP[t*4+1] = e1 * inv; LP[t*4+2] = e2 * inv; LP[t*4+3] = e3 * inv;
}

// ---- fused: all-4-expert GEMM + gated combine -> fp32 out ----
__global__ __launch_bounds__(256)
void k_expert_fused(const float* __restrict__ feat, const float* __restrict__ We,
                    const float* __restrict__ eb, const float* __restrict__ P,
                    float* __restrict__ out, int m0, int Tc) {
  __shared__ float As[16][68];
  __shared__ float Bs[4][16][68];
  const int bm = blockIdx.x, bn = blockIdx.y;
  const int tid = threadIdx.x, tx = tid & 15, ty = tid >> 4;
  float acc[4][4][4] = {};   // [d][i][j]
  for (int k0 = 0; k0 < F2; k0 += 16) {
    __syncthreads();
    #pragma unroll
    for (int e = 0; e < 4; ++e) {
      int idx = tid + 256 * e;
      int r = idx >> 4, kk = idx & 15;
      As[kk][r] = feat[(size_t)(bm * 64 + r) * F2 + k0 + kk];
    }
    #pragma unroll
    for (int d = 0; d < 4; ++d)
      #pragma unroll
      for (int e = 0; e < 4; ++e) {
        int idx = tid + 256 * e;
        int kk = idx >> 6, c = idx & 63;
        Bs[d][kk][c] = We[((size_t)d * F2 + k0 + kk) * Hh + bn * 64 + c];
      }
    __syncthreads();
    #pragma unroll
    for (int kk = 0; kk < 16; ++kk) {
      float4 a4 = *(const float4*)&As[kk][ty * 4];
      float av[4] = {a4.x, a4.y, a4.z, a4.w};
      #pragma unroll
      for (int d = 0; d < 4; ++d) {
        float4 b4 = *(const float4*)&Bs[d][kk][tx * 4];
        float bv[4] = {b4.x, b4.y, b4.z, b4.w};
        #pragma unroll
        for (int i = 0; i < 4; ++i)
          #pragma unroll
          for (int j = 0; j < 4; ++j)
            acc[d][i][j] += av[i] * bv[j];
      }
    }
  }
  #pragma unroll
  for (int i = 0; i < 4; ++i) {
    int t = bm * 64 + ty * 4 + i;     // chunk-local token
    float p0 = P[t*4+0], p1 = P[t*4+1], p2 = P[t*4+2], p3 = P[t*4+3];
    #pragma unroll
    for (int j = 0; j < 4; ++j) {
      int gn = bn * 64 + tx * 4 + j;
      float r = p0 * (acc[0][i][j] + eb[gn])
              + p1 * (acc[1][i][j] + eb[Hh + gn])
              + p2 * (acc[2][i][j] + eb[2 * Hh + gn])
              + p3 * (acc[3][i][j] + eb[3 * Hh + gn]);
      out[(size_t)(m0 + t) * Hh + gn] = r;   // fp32 output
    }
  }
}

extern "C" void kernel_launch(void* const* d_in, const int* in_sizes, int n_in,
                              void* d_out, int out_size, void* d_ws, size_t ws_size,
                              hipStream_t stream) {
  const float *x  = (const float*)d_in[0],  *vol = (const float*)d_in[1];
  const float *risk = (const float*)d_in[2], *Wf = (const float*)d_in[3];
  const float *fb = (const float*)d_in[4],  *Wc = (const float*)d_in[5];
  const float *cb = (const float*)d_in[6],  *vw = (const float*)d_in[7];
  const float *vb = (const float*)d_in[8],  *rw = (const float*)d_in[9];
  const float *rb = (const float*)d_in[10], *sw = (const float*)d_in[11];
  const float *sb = (const float*)d_in[12], *We = (const float*)d_in[13];
  const float *eb = (const float*)d_in[14];

  float* out = (float*)d_out;   // reference output dtype = float32
  char* ws = (char*)d_ws;

  // ---- choose chunk so (feat fp32 + LP) fits in ws; floor Tc=64 (0.53 MB) ----
  int Tc = TOK;
  while (Tc > 64 && (size_t)Tc * F2 * 4 + (size_t)Tc * 16 > ws_size) Tc >>= 1;
  float* feat = (float*)ws;                              // Tc * 8 KB
  float* LP   = (float*)(ws + (size_t)Tc * F2 * 4);      // Tc * 16 B (logits, then P)

  for (int m0 = 0; m0 < TOK; m0 += Tc) {
    k_router_t<<<(Tc + 255) / 256, 256, 0, stream>>>(
        x, vol, risk, cb, vw, vb, rw, rb, sw, sb, LP, m0, Tc);
    k_feat32<<<dim3(Tc / 64, F2 / 64), 256, 0, stream>>>(
        x + (size_t)m0 * Hh, Wf, fb, feat);
    k_dom_t<<<(Tc + 255) / 256, 256, 0, stream>>>(feat, Wc, LP, Tc);
    k_expert_fused<<<dim3(Tc / 64, Hh / 64), 256, 0, stream>>>(
        feat, We, eb, LP, out, m0, Tc);
  }
}

// Round 6
// 631.823 us; speedup vs baseline: 10.0037x; 10.0037x over previous
//
#include <hip/hip_runtime.h>
#include <hip/hip_bf16.h>
#include <cstdint>
#include <cstddef>

typedef __bf16 bf16_t;
typedef bf16_t bf16x8 __attribute__((ext_vector_type(8)));
typedef bf16_t bf16x4 __attribute__((ext_vector_type(4)));
typedef float  f32x4  __attribute__((ext_vector_type(4)));

#define TOK 16384   // B*S
#define Hh  1024    // hidden
#define F2  2048    // 2*H
#define NC  4096    // interleaved expert cols: h*4+d

__device__ __forceinline__ void gload_lds16(const bf16_t* g, bf16_t* lds) {
  __builtin_amdgcn_global_load_lds(
      (const __attribute__((address_space(1))) void*)g,
      (__attribute__((address_space(3))) void*)lds, 16, 0, 0);
}

// ---------------- x fp32 -> bf16 ----------------
__global__ void k_cvt_x(const float* __restrict__ x, bf16_t* __restrict__ o) {
  int i = blockIdx.x * blockDim.x + threadIdx.x;
  int stride = gridDim.x * blockDim.x;
  const float4* x4 = (const float4*)x;
  for (int j = i; j < TOK * Hh / 4; j += stride) {
    float4 v = x4[j];
    bf16x4 r = { (bf16_t)v.x, (bf16_t)v.y, (bf16_t)v.z, (bf16_t)v.w };
    *(bf16x4*)(o + (size_t)j * 4) = r;
  }
}

// ---- Wf [1024][2048] fp32 -> wft [2048][1024] bf16 (tiled transpose) ----
__global__ __launch_bounds__(256)
void k_tr_wf(const float* __restrict__ in, bf16_t* __restrict__ out) {
  __shared__ float T[64][65];            // T[f][h]
  const int f0 = blockIdx.x * 64, h0 = blockIdx.y * 64;
  const int tid = threadIdx.x;
  const int c4 = (tid & 15) * 4, r = tid >> 4;
  #pragma unroll
  for (int p = 0; p < 4; ++p) {
    int hh = p * 16 + r;                 // input row (h), cols f coalesced
    float4 v = *(const float4*)&in[(size_t)(h0 + hh) * F2 + f0 + c4];
    T[c4 + 0][hh] = v.x; T[c4 + 1][hh] = v.y; T[c4 + 2][hh] = v.z; T[c4 + 3][hh] = v.w;
  }
  __syncthreads();
  #pragma unroll
  for (int p = 0; p < 4; ++p) {
    int ff = p * 16 + r;                 // output row (f), cols h coalesced
    bf16x4 o = { (bf16_t)T[ff][c4 + 0], (bf16_t)T[ff][c4 + 1],
                 (bf16_t)T[ff][c4 + 2], (bf16_t)T[ff][c4 + 3] };
    *(bf16x4*)&out[(size_t)(f0 + ff) * Hh + h0 + c4] = o;
  }
}

// ---- We [4][2048][1024] fp32 -> wet [4096][2048] bf16, row cp = h*4+d ----
__global__ __launch_bounds__(256)
void k_tr_we(const float* __restrict__ in, bf16_t* __restrict__ out) {
  __shared__ float T[64][65];            // T[h][f]
  const int f0 = blockIdx.x * 64, h0 = blockIdx.y * 64, d = blockIdx.z;
  const float* ind = in + (size_t)d * F2 * Hh;
  const int tid = threadIdx.x;
  const int c4 = (tid & 15) * 4, r = tid >> 4;
  #pragma unroll
  for (int p = 0; p < 4; ++p) {
    int ff = p * 16 + r;                 // input row (f), cols h coalesced
    float4 v = *(const float4*)&ind[(size_t)(f0 + ff) * Hh + h0 + c4];
    T[c4 + 0][ff] = v.x; T[c4 + 1][ff] = v.y; T[c4 + 2][ff] = v.z; T[c4 + 3][ff] = v.w;
  }
  __syncthreads();
  #pragma unroll
  for (int p = 0; p < 4; ++p) {
    int hh = p * 16 + r;                 // output row cp=(h0+hh)*4+d, cols f coalesced
    bf16x4 o = { (bf16_t)T[hh][c4 + 0], (bf16_t)T[hh][c4 + 1],
                 (bf16_t)T[hh][c4 + 2], (bf16_t)T[hh][c4 + 3] };
    *(bf16x4*)&out[(size_t)((h0 + hh) * 4 + d) * F2 + f0 + c4] = o;
  }
}

// ---- per-token router logits (thread per token; verified green) ----
__global__ void k_router_t(const float* __restrict__ x, const float* __restrict__ vol,
                           const float* __restrict__ risk, const float* __restrict__ clsb,
                           const float* __restrict__ vw, const float* __restrict__ vb,
                           const float* __restrict__ rw, const float* __restrict__ rb,
                           const float* __restrict__ sw, const float* __restrict__ sb,
                           float* __restrict__ LP, int m0, int Tc) {
  int t = blockIdx.x * blockDim.x + threadIdx.x;
  if (t >= Tc) return;
  int s = m0 + t;
  const float4* xr = (const float4*)(x + (size_t)s * Hh);
  float sum = 0.f, sq = 0.f, mx = -1e30f;
  for (int i = 0; i < Hh / 4; ++i) {
    float4 v = xr[i];
    sum += v.x + v.y + v.z + v.w;
    sq  += v.x * v.x + v.y * v.y + v.z * v.z + v.w * v.w;
    mx = fmaxf(mx, fmaxf(fmaxf(v.x, v.y), fmaxf(v.z, v.w)));
  }
  float mean = sum * (1.0f / Hh);
  float var  = sq * (1.0f / Hh) - mean * mean;
  float sd   = sqrtf(fmaxf(var, 0.f));
  float v = vol[s], rk = risk[s];
  #pragma unroll
  for (int d = 0; d < 4; ++d) {
    float acc = clsb[d];
    #pragma unroll
    for (int k = 0; k < 8; ++k)  acc += tanhf(v  * vw[k*4+d] + vb[k*4+d]);
    #pragma unroll
    for (int k = 0; k < 8; ++k)  acc += tanhf(rk * rw[k*4+d] + rb[k*4+d]);
    #pragma unroll
    for (int k = 0; k < 12; ++k)
      acc += tanhf(mean * sw[k*4+d] + sd * sw[48 + k*4+d] + mx * sw[96 + k*4+d] + sb[k*4+d]);
    LP[t * 4 + d] = acc;
  }
}

// ---------------- GEMM 1 (MFMA): feat = tanh(xbf @ wft^T + fb), bf16 out ----------------
__global__ __launch_bounds__(256, 2)
void k_feat_gemm(const bf16_t* __restrict__ A,   // [Tc][1024]
                 const bf16_t* __restrict__ Bt,  // [2048][1024]
                 const float* __restrict__ bias, // [2048]
                 bf16_t* __restrict__ feat) {    // [Tc][2048]
  constexpr int K = Hh;
  __shared__ bf16_t As[128 * 64];
  __shared__ bf16_t Bs[128 * 64];
  const int bm = blockIdx.x, bn = blockIdx.y;
  const int tid = threadIdx.x;
  const int w = tid >> 6, l = tid & 63;
  const int wm = (w >> 1) * 64, wn = (w & 1) * 64;
  f32x4 acc[4][4] = {};
  for (int kk = 0; kk < K; kk += 64) {
    __syncthreads();
    #pragma unroll
    for (int c = 0; c < 4; ++c) {
      int q = (w * 4 + c) * 64 + l;
      int row = q >> 3, slot = q & 7;
      gload_lds16(A  + (size_t)(bm * 128 + row) * K + kk + slot * 8, &As[(w * 4 + c) * 512]);
      gload_lds16(Bt + (size_t)(bn * 128 + row) * K + kk + slot * 8, &Bs[(w * 4 + c) * 512]);
    }
    __syncthreads();
    #pragma unroll
    for (int ks = 0; ks < 2; ++ks) {
      bf16x8 av[4], bv[4];
      #pragma unroll
      for (int mi = 0; mi < 4; ++mi)
        av[mi] = *(const bf16x8*)&As[(wm + mi * 16 + (l & 15)) * 64 + ks * 32 + (l >> 4) * 8];
      #pragma unroll
      for (int ni = 0; ni < 4; ++ni)
        bv[ni] = *(const bf16x8*)&Bs[(wn + ni * 16 + (l & 15)) * 64 + ks * 32 + (l >> 4) * 8];
      #pragma unroll
      for (int mi = 0; mi < 4; ++mi)
        #pragma unroll
        for (int ni = 0; ni < 4; ++ni)
          acc[mi][ni] = __builtin_amdgcn_mfma_f32_16x16x32_bf16(av[mi], bv[ni], acc[mi][ni], 0, 0, 0);
    }
  }
  #pragma unroll
  for (int mi = 0; mi < 4; ++mi)
    #pragma unroll
    for (int ni = 0; ni < 4; ++ni) {
      int gn = bn * 128 + wn + ni * 16 + (l & 15);
      float bv = bias[gn];
      #pragma unroll
      for (int r = 0; r < 4; ++r) {
        int gm = bm * 128 + wm + mi * 16 + (l >> 4) * 4 + r;
        feat[(size_t)gm * F2 + gn] = (bf16_t)tanhf(acc[mi][ni][r] + bv);
      }
    }
}

// ---- dom logits + softmax (wave per token, bf16x8 loads), in-place LP ----
__global__ void k_dom(const bf16_t* __restrict__ feat, const float* __restrict__ Wc,
                      float* __restrict__ LP) {
  int w = threadIdx.x >> 6, l = threadIdx.x & 63;
  int t = blockIdx.x * 4 + w;
  const bf16_t* fr = feat + (size_t)t * F2;
  const float4* Wc4 = (const float4*)Wc;
  float a0 = 0, a1 = 0, a2 = 0, a3 = 0;
  #pragma unroll
  for (int it = 0; it < 4; ++it) {
    int f0 = it * 512 + l * 8;
    bf16x8 v = *(const bf16x8*)(fr + f0);
    #pragma unroll
    for (int j = 0; j < 8; ++j) {
      float vf = (float)v[j];
      float4 wv = Wc4[f0 + j];
      a0 += vf * wv.x; a1 += vf * wv.y; a2 += vf * wv.z; a3 += vf * wv.w;
    }
  }
  #pragma unroll
  for (int off = 32; off; off >>= 1) {
    a0 += __shfl_xor(a0, off, 64); a1 += __shfl_xor(a1, off, 64);
    a2 += __shfl_xor(a2, off, 64); a3 += __shfl_xor(a3, off, 64);
  }
  if (l == 0) {
    float l0 = a0 + LP[t*4+0], l1 = a1 + LP[t*4+1];
    float l2 = a2 + LP[t*4+2], l3 = a3 + LP[t*4+3];
    float m = fmaxf(fmaxf(l0, l1), fmaxf(l2, l3));
    float e0 = expf(l0 - m), e1 = expf(l1 - m), e2 = expf(l2 - m), e3 = expf(l3 - m);
    float inv = 1.f / (e0 + e1 + e2 + e3);
    LP[t*4+0] = e0 * inv; LP[t*4+1] = e1 * inv; LP[t*4+2] = e2 * inv; LP[t*4+3] = e3 * inv;
  }
}

// ---------------- GEMM 2 (MFMA): expert dispatch + gated combine -> fp32 ----------------
__global__ __launch_bounds__(256, 2)
void k_expert_gemm(const bf16_t* __restrict__ A,   // feat [Tc][2048]
                   const bf16_t* __restrict__ Bt,  // wet [4096][2048]
                   const float* __restrict__ P,    // [Tc][4]
                   const float* __restrict__ EB,   // [4][1024]
                   float* __restrict__ out) {      // [Tc][1024] fp32
  constexpr int K = F2;
  __shared__ bf16_t As[128 * 64];
  __shared__ bf16_t Bs[128 * 64];
  const int bm = blockIdx.x, bn = blockIdx.y;
  const int tid = threadIdx.x;
  const int w = tid >> 6, l = tid & 63;
  const int wm = (w >> 1) * 64, wn = (w & 1) * 64;
  f32x4 acc[4][4] = {};
  for (int kk = 0; kk < K; kk += 64) {
    __syncthreads();
    #pragma unroll
    for (int c = 0; c < 4; ++c) {
      int q = (w * 4 + c) * 64 + l;
      int row = q >> 3, slot = q & 7;
      gload_lds16(A  + (size_t)(bm * 128 + row) * K + kk + slot * 8, &As[(w * 4 + c) * 512]);
      gload_lds16(Bt + (size_t)(bn * 128 + row) * K + kk + slot * 8, &Bs[(w * 4 + c) * 512]);
    }
    __syncthreads();
    #pragma unroll
    for (int ks = 0; ks < 2; ++ks) {
      bf16x8 av[4], bv[4];
      #pragma unroll
      for (int mi = 0; mi < 4; ++mi)
        av[mi] = *(const bf16x8*)&As[(wm + mi * 16 + (l & 15)) * 64 + ks * 32 + (l >> 4) * 8];
      #pragma unroll
      for (int ni = 0; ni < 4; ++ni)
        bv[ni] = *(const bf16x8*)&Bs[(wn + ni * 16 + (l & 15)) * 64 + ks * 32 + (l >> 4) * 8];
      #pragma unroll
      for (int mi = 0; mi < 4; ++mi)
        #pragma unroll
        for (int ni = 0; ni < 4; ++ni)
          acc[mi][ni] = __builtin_amdgcn_mfma_f32_16x16x32_bf16(av[mi], bv[ni], acc[mi][ni], 0, 0, 0);
    }
  }
  // epilogue: cols 4h..4h+3 live in lanes l&~3 .. l|3 -> gate+reduce via shfl
  float pv[4][4];
  #pragma unroll
  for (int mi = 0; mi < 4; ++mi)
    #pragma unroll
    for (int r = 0; r < 4; ++r) {
      int gm = bm * 128 + wm + mi * 16 + (l >> 4) * 4 + r;
      pv[mi][r] = P[gm * 4 + (l & 3)];
    }
  #pragma unroll
  for (int mi = 0; mi < 4; ++mi)
    #pragma unroll
    for (int ni = 0; ni < 4; ++ni) {
      int colp = bn * 128 + wn + ni * 16 + (l & 15);
      int h = colp >> 2;
      #pragma unroll
      for (int r = 0; r < 4; ++r) {
        int gm = bm * 128 + wm + mi * 16 + (l >> 4) * 4 + r;
        float sv = acc[mi][ni][r] * pv[mi][r];
        sv += __shfl_xor(sv, 1, 64);
        sv += __shfl_xor(sv, 2, 64);
        if ((l & 3) == 0) {
          float bt = P[gm*4+0]*EB[h] + P[gm*4+1]*EB[Hh+h] + P[gm*4+2]*EB[2*Hh+h] + P[gm*4+3]*EB[3*Hh+h];
          out[(size_t)gm * Hh + h] = sv + bt;
        }
      }
    }
}

extern "C" void kernel_launch(void* const* d_in, const int* in_sizes, int n_in,
                              void* d_out, int out_size, void* d_ws, size_t ws_size,
                              hipStream_t stream) {
  const float *x  = (const float*)d_in[0],  *vol = (const float*)d_in[1];
  const float *risk = (const float*)d_in[2], *Wf = (const float*)d_in[3];
  const float *fb = (const float*)d_in[4],  *Wc = (const float*)d_in[5];
  const float *cb = (const float*)d_in[6],  *vw = (const float*)d_in[7];
  const float *vb = (const float*)d_in[8],  *rw = (const float*)d_in[9];
  const float *rb = (const float*)d_in[10], *sw = (const float*)d_in[11];
  const float *sb = (const float*)d_in[12], *We = (const float*)d_in[13];
  const float *eb = (const float*)d_in[14];

  float* out = (float*)d_out;   // fp32 output (confirmed round 5)
  char* ws = (char*)d_ws;
  const size_t KB = 1024, MB = 1024 * 1024;

  // layout: LP 256KB | wft 4MB | wet 16MB | xbf 32MB | feat Tc*4KB
  float*  LP  = (float*) ws;
  bf16_t* wft = (bf16_t*)(ws + 256 * KB);
  bf16_t* wet = (bf16_t*)(ws + 256 * KB + 4 * MB);
  bf16_t* xbf = (bf16_t*)(ws + 256 * KB + 20 * MB);
  const size_t base = 256 * KB + 52 * MB;
  int Tc = TOK;
  while (Tc > 1024 && base + (size_t)Tc * F2 * sizeof(bf16_t) > ws_size) Tc >>= 1;
  bf16_t* feat = (bf16_t*)(ws + base);

  k_cvt_x <<<2048, 256, 0, stream>>>(x, xbf);
  k_tr_wf <<<dim3(F2 / 64, Hh / 64), 256, 0, stream>>>(Wf, wft);
  k_tr_we <<<dim3(F2 / 64, Hh / 64, 4), 256, 0, stream>>>(We, wet);

  for (int m0 = 0; m0 < TOK; m0 += Tc) {
    k_router_t<<<(Tc + 255) / 256, 256, 0, stream>>>(
        x, vol, risk, cb, vw, vb, rw, rb, sw, sb, LP, m0, Tc);
    k_feat_gemm<<<dim3(Tc / 128, F2 / 128), 256, 0, stream>>>(
        xbf + (size_t)m0 * Hh, wft, fb, feat);
    k_dom<<<Tc / 4, 256, 0, stream>>>(feat, Wc, LP);
    k_expert_gemm<<<dim3(Tc / 128, NC / 128), 256, 0, stream>>>(
        feat, wet, LP, eb, out + (size_t)m0 * Hh);
  }
}

// Round 7
// 589.699 us; speedup vs baseline: 10.7183x; 1.0714x over previous
//
#include <hip/hip_runtime.h>
#include <hip/hip_bf16.h>
#include <cstdint>
#include <cstddef>

typedef __bf16 bf16_t;
typedef bf16_t bf16x8 __attribute__((ext_vector_type(8)));
typedef bf16_t bf16x4 __attribute__((ext_vector_type(4)));
typedef float  f32x4  __attribute__((ext_vector_type(4)));

#define TOK 16384   // B*S
#define Hh  1024    // hidden
#define F2  2048    // 2*H
#define NC  4096    // interleaved expert cols: h*4+d

__device__ __forceinline__ void gload_lds16(const bf16_t* g, bf16_t* lds) {
  __builtin_amdgcn_global_load_lds(
      (const __attribute__((address_space(1))) void*)g,
      (__attribute__((address_space(3))) void*)lds, 16, 0, 0);
}

// ---------------- x fp32 -> bf16 ----------------
__global__ void k_cvt_x(const float* __restrict__ x, bf16_t* __restrict__ o) {
  int i = blockIdx.x * blockDim.x + threadIdx.x;
  int stride = gridDim.x * blockDim.x;
  const float4* x4 = (const float4*)x;
  for (int j = i; j < TOK * Hh / 4; j += stride) {
    float4 v = x4[j];
    bf16x4 r = { (bf16_t)v.x, (bf16_t)v.y, (bf16_t)v.z, (bf16_t)v.w };
    *(bf16x4*)(o + (size_t)j * 4) = r;
  }
}

// ---- Wf [1024][2048] fp32 -> wft [2048][1024] bf16 (tiled transpose) ----
__global__ __launch_bounds__(256)
void k_tr_wf(const float* __restrict__ in, bf16_t* __restrict__ out) {
  __shared__ float T[64][65];            // T[f][h]
  const int f0 = blockIdx.x * 64, h0 = blockIdx.y * 64;
  const int tid = threadIdx.x;
  const int c4 = (tid & 15) * 4, r = tid >> 4;
  #pragma unroll
  for (int p = 0; p < 4; ++p) {
    int hh = p * 16 + r;
    float4 v = *(const float4*)&in[(size_t)(h0 + hh) * F2 + f0 + c4];
    T[c4 + 0][hh] = v.x; T[c4 + 1][hh] = v.y; T[c4 + 2][hh] = v.z; T[c4 + 3][hh] = v.w;
  }
  __syncthreads();
  #pragma unroll
  for (int p = 0; p < 4; ++p) {
    int ff = p * 16 + r;
    bf16x4 o = { (bf16_t)T[ff][c4 + 0], (bf16_t)T[ff][c4 + 1],
                 (bf16_t)T[ff][c4 + 2], (bf16_t)T[ff][c4 + 3] };
    *(bf16x4*)&out[(size_t)(f0 + ff) * Hh + h0 + c4] = o;
  }
}

// ---- We [4][2048][1024] fp32 -> wet [4096][2048] bf16, row cp = h*4+d ----
__global__ __launch_bounds__(256)
void k_tr_we(const float* __restrict__ in, bf16_t* __restrict__ out) {
  __shared__ float T[64][65];            // T[h][f]
  const int f0 = blockIdx.x * 64, h0 = blockIdx.y * 64, d = blockIdx.z;
  const float* ind = in + (size_t)d * F2 * Hh;
  const int tid = threadIdx.x;
  const int c4 = (tid & 15) * 4, r = tid >> 4;
  #pragma unroll
  for (int p = 0; p < 4; ++p) {
    int ff = p * 16 + r;
    float4 v = *(const float4*)&ind[(size_t)(f0 + ff) * Hh + h0 + c4];
    T[c4 + 0][ff] = v.x; T[c4 + 1][ff] = v.y; T[c4 + 2][ff] = v.z; T[c4 + 3][ff] = v.w;
  }
  __syncthreads();
  #pragma unroll
  for (int p = 0; p < 4; ++p) {
    int hh = p * 16 + r;
    bf16x4 o = { (bf16_t)T[hh][c4 + 0], (bf16_t)T[hh][c4 + 1],
                 (bf16_t)T[hh][c4 + 2], (bf16_t)T[hh][c4 + 3] };
    *(bf16x4*)&out[(size_t)((h0 + hh) * 4 + d) * F2 + f0 + c4] = o;
  }
}

// ---- per-token router logits ----
__global__ void k_router_t(const float* __restrict__ x, const float* __restrict__ vol,
                           const float* __restrict__ risk, const float* __restrict__ clsb,
                           const float* __restrict__ vw, const float* __restrict__ vb,
                           const float* __restrict__ rw, const float* __restrict__ rb,
                           const float* __restrict__ sw, const float* __restrict__ sb,
                           float* __restrict__ LP, int m0, int Tc) {
  int t = blockIdx.x * blockDim.x + threadIdx.x;
  if (t >= Tc) return;
  int s = m0 + t;
  const float4* xr = (const float4*)(x + (size_t)s * Hh);
  float sum = 0.f, sq = 0.f, mx = -1e30f;
  for (int i = 0; i < Hh / 4; ++i) {
    float4 v = xr[i];
    sum += v.x + v.y + v.z + v.w;
    sq  += v.x * v.x + v.y * v.y + v.z * v.z + v.w * v.w;
    mx = fmaxf(mx, fmaxf(fmaxf(v.x, v.y), fmaxf(v.z, v.w)));
  }
  float mean = sum * (1.0f / Hh);
  float var  = sq * (1.0f / Hh) - mean * mean;
  float sd   = sqrtf(fmaxf(var, 0.f));
  float v = vol[s], rk = risk[s];
  #pragma unroll
  for (int d = 0; d < 4; ++d) {
    float acc = clsb[d];
    #pragma unroll
    for (int k = 0; k < 8; ++k)  acc += tanhf(v  * vw[k*4+d] + vb[k*4+d]);
    #pragma unroll
    for (int k = 0; k < 8; ++k)  acc += tanhf(rk * rw[k*4+d] + rb[k*4+d]);
    #pragma unroll
    for (int k = 0; k < 12; ++k)
      acc += tanhf(mean * sw[k*4+d] + sd * sw[48 + k*4+d] + mx * sw[96 + k*4+d] + sb[k*4+d]);
    LP[t * 4 + d] = acc;
  }
}

// ---------------- GEMM 1 (MFMA 128^2, m97-style): feat = tanh(xbf @ wft^T + fb) ----------------
__global__ __launch_bounds__(256, 2)
void k_feat_gemm(const bf16_t* __restrict__ A,   // [Tc][1024]
                 const bf16_t* __restrict__ Bt,  // [2048][1024]
                 const float* __restrict__ bias, // [2048]
                 bf16_t* __restrict__ feat) {    // [Tc][2048]
  constexpr int K = Hh;
  __shared__ bf16_t As[128 * 64];
  __shared__ bf16_t Bs[128 * 64];
  const int bm = blockIdx.x, bn = blockIdx.y;
  const int tid = threadIdx.x;
  const int w = tid >> 6, l = tid & 63;
  const int wm = (w >> 1) * 64, wn = (w & 1) * 64;
  f32x4 acc[4][4] = {};
  for (int kk = 0; kk < K; kk += 64) {
    __syncthreads();
    #pragma unroll
    for (int c = 0; c < 4; ++c) {
      int q = (w * 4 + c) * 64 + l;
      int row = q >> 3, slot = q & 7;
      gload_lds16(A  + (size_t)(bm * 128 + row) * K + kk + slot * 8, &As[(w * 4 + c) * 512]);
      gload_lds16(Bt + (size_t)(bn * 128 + row) * K + kk + slot * 8, &Bs[(w * 4 + c) * 512]);
    }
    __syncthreads();
    #pragma unroll
    for (int ks = 0; ks < 2; ++ks) {
      bf16x8 av[4], bv[4];
      #pragma unroll
      for (int mi = 0; mi < 4; ++mi)
        av[mi] = *(const bf16x8*)&As[(wm + mi * 16 + (l & 15)) * 64 + ks * 32 + (l >> 4) * 8];
      #pragma unroll
      for (int ni = 0; ni < 4; ++ni)
        bv[ni] = *(const bf16x8*)&Bs[(wn + ni * 16 + (l & 15)) * 64 + ks * 32 + (l >> 4) * 8];
      #pragma unroll
      for (int mi = 0; mi < 4; ++mi)
        #pragma unroll
        for (int ni = 0; ni < 4; ++ni)
          acc[mi][ni] = __builtin_amdgcn_mfma_f32_16x16x32_bf16(av[mi], bv[ni], acc[mi][ni], 0, 0, 0);
    }
  }
  #pragma unroll
  for (int mi = 0; mi < 4; ++mi)
    #pragma unroll
    for (int ni = 0; ni < 4; ++ni) {
      int gn = bn * 128 + wn + ni * 16 + (l & 15);
      float bv = bias[gn];
      #pragma unroll
      for (int r = 0; r < 4; ++r) {
        int gm = bm * 128 + wm + mi * 16 + (l >> 4) * 4 + r;
        feat[(size_t)gm * F2 + gn] = (bf16_t)tanhf(acc[mi][ni][r] + bv);
      }
    }
}

// ---- dom logits + softmax (wave per token), in-place LP ----
__global__ void k_dom(const bf16_t* __restrict__ feat, const float* __restrict__ Wc,
                      float* __restrict__ LP) {
  int w = threadIdx.x >> 6, l = threadIdx.x & 63;
  int t = blockIdx.x * 4 + w;
  const bf16_t* fr = feat + (size_t)t * F2;
  const float4* Wc4 = (const float4*)Wc;
  float a0 = 0, a1 = 0, a2 = 0, a3 = 0;
  #pragma unroll
  for (int it = 0; it < 4; ++it) {
    int f0 = it * 512 + l * 8;
    bf16x8 v = *(const bf16x8*)(fr + f0);
    #pragma unroll
    for (int j = 0; j < 8; ++j) {
      float vf = (float)v[j];
      float4 wv = Wc4[f0 + j];
      a0 += vf * wv.x; a1 += vf * wv.y; a2 += vf * wv.z; a3 += vf * wv.w;
    }
  }
  #pragma unroll
  for (int off = 32; off; off >>= 1) {
    a0 += __shfl_xor(a0, off, 64); a1 += __shfl_xor(a1, off, 64);
    a2 += __shfl_xor(a2, off, 64); a3 += __shfl_xor(a3, off, 64);
  }
  if (l == 0) {
    float l0 = a0 + LP[t*4+0], l1 = a1 + LP[t*4+1];
    float l2 = a2 + LP[t*4+2], l3 = a3 + LP[t*4+3];
    float m = fmaxf(fmaxf(l0, l1), fmaxf(l2, l3));
    float e0 = expf(l0 - m), e1 = expf(l1 - m), e2 = expf(l2 - m), e3 = expf(l3 - m);
    float inv = 1.f / (e0 + e1 + e2 + e3);
    LP[t*4+0] = e0 * inv; LP[t*4+1] = e1 * inv; LP[t*4+2] = e2 * inv; LP[t*4+3] = e3 * inv;
  }
}

// ---------------- GEMM 2: 256x256, counted-vmcnt dbuf, T2 swizzle, T5 setprio ----------------
// feat [Tc][2048] x wet [4096][2048]^T -> gated combine -> out [Tc][1024] fp32
__global__ __launch_bounds__(512, 1)
void k_expert_gemm256(const bf16_t* __restrict__ A, const bf16_t* __restrict__ Bt,
                      const float* __restrict__ P, const float* __restrict__ EB,
                      float* __restrict__ out, int nbm) {
  constexpr int K = F2, NT = K / 64;   // 32 K-tiles
  __shared__ bf16_t As[2][256 * 64];   // [dbuf][2 halves of [128][64], swizzled]
  __shared__ bf16_t Bs[2][256 * 64];
  const int tid = threadIdx.x;
  const int l = tid & 63, wid = tid >> 6;
  const int wm = wid >> 2, wn = wid & 3;     // wave row (0..1) / col (0..3)
  const int l15 = l & 15, lg = l >> 4;

  // XCD-bijective block swizzle (nwg = nbm*16, multiple of 8)
  const int nwg = nbm * 16, cpx = nwg >> 3;
  int swzb = (blockIdx.x & 7) * cpx + (blockIdx.x >> 3);
  const int bm = swzb % nbm, bn = swzb / nbm;

  const bf16_t* gA = A  + (size_t)(bm * 256) * K;
  const bf16_t* gB = Bt + (size_t)(bn * 256) * K;

  // staging slot precompute: slot = a*512+tid; dest byte D=slot*16 (linear, lane-contig);
  // source = inverse-swizzled (involution) global address
  int s_row[4], s_cb[4];
  #pragma unroll
  for (int a = 0; a < 4; ++a) {
    int slot = a * 512 + tid;
    int h = slot >> 10;                       // half (0/1) -> rows +128
    int r = (slot & 1023) >> 3;               // row within half
    s_row[a] = h * 128 + r;
    s_cb[a] = ((slot & 7) * 16) ^ ((r & 7) << 4);   // swizzled col byte
  }

  #define STAGE(t, b) do {                                                        \
    const bf16_t* a0_ = gA + (t) * 64;                                            \
    const bf16_t* b0_ = gB + (t) * 64;                                            \
    _Pragma("unroll")                                                             \
    for (int a = 0; a < 4; ++a)                                                   \
      gload_lds16(a0_ + (size_t)s_row[a] * K + (s_cb[a] >> 1),                    \
                  &As[b][(a * 512 + tid) * 8]);                                   \
    _Pragma("unroll")                                                             \
    for (int a = 0; a < 4; ++a)                                                   \
      gload_lds16(b0_ + (size_t)s_row[a] * K + (s_cb[a] >> 1),                    \
                  &Bs[b][(a * 512 + tid) * 8]);                                   \
  } while (0)

  // read-side swizzled col offsets (elements): ((ks*64 + lg*16) ^ ((l&7)<<4)) / 2
  const int cs0 = ((lg * 16)      ^ ((l & 7) << 4)) >> 1;
  const int cs1 = ((64 + lg * 16) ^ ((l & 7) << 4)) >> 1;
  const int aBase = wm * 8192;               // wave's A half (elements)
  const int bBase = (wn >> 1) * 8192;        // wave's B half
  const int bRL0 = (wn & 1) * 64;

  f32x4 acc[8][4] = {};

  STAGE(0, 0);
  STAGE(1, 1);

  for (int t = 0; t < NT; ++t) {
    const int b = t & 1;
    if (t < NT - 1) asm volatile("s_waitcnt vmcnt(8)" ::: "memory");
    else            asm volatile("s_waitcnt vmcnt(0)" ::: "memory");
    __builtin_amdgcn_s_barrier();
    asm volatile("" ::: "memory");

    bf16x8 bf[2][4];
    #pragma unroll
    for (int ni = 0; ni < 4; ++ni) {
      int rl = (bRL0 + ni * 16 + l15) * 64;
      bf[0][ni] = *(const bf16x8*)&Bs[b][bBase + rl + cs0];
      bf[1][ni] = *(const bf16x8*)&Bs[b][bBase + rl + cs1];
    }
    #pragma unroll
    for (int q = 0; q < 4; ++q) {
      bf16x8 af[2][2];
      #pragma unroll
      for (int m2 = 0; m2 < 2; ++m2) {
        int rl = ((q * 2 + m2) * 16 + l15) * 64;
        af[0][m2] = *(const bf16x8*)&As[b][aBase + rl + cs0];
        af[1][m2] = *(const bf16x8*)&As[b][aBase + rl + cs1];
      }
      __builtin_amdgcn_s_setprio(1);
      #pragma unroll
      for (int ks = 0; ks < 2; ++ks)
        #pragma unroll
        for (int m2 = 0; m2 < 2; ++m2)
          #pragma unroll
          for (int ni = 0; ni < 4; ++ni)
            acc[q * 2 + m2][ni] = __builtin_amdgcn_mfma_f32_16x16x32_bf16(
                af[ks][m2], bf[ks][ni], acc[q * 2 + m2][ni], 0, 0, 0);
      __builtin_amdgcn_s_setprio(0);
    }
    asm volatile("" ::: "memory");
    __builtin_amdgcn_s_barrier();
    asm volatile("" ::: "memory");
    if (t < NT - 2) STAGE(t + 2, b);
  }
  #undef STAGE

  // epilogue: gated combine (cols 4h..4h+3 in lane quad) -> fp32 out
  #pragma unroll
  for (int mi = 0; mi < 8; ++mi) {
    int gmBase = bm * 256 + wm * 128 + mi * 16 + lg * 4;
    float pr[4];
    #pragma unroll
    for (int r = 0; r < 4; ++r) pr[r] = P[(gmBase + r) * 4 + (l & 3)];
    #pragma unroll
    for (int ni = 0; ni < 4; ++ni) {
      int colp = bn * 256 + wn * 64 + ni * 16 + l15;
      int h = colp >> 2;
      #pragma unroll
      for (int r = 0; r < 4; ++r) {
        float sv = acc[mi][ni][r] * pr[r];
        sv += __shfl_xor(sv, 1, 64);
        sv += __shfl_xor(sv, 2, 64);
        if ((l & 3) == 0) {
          int gm = gmBase + r;
          float bt = P[gm*4+0]*EB[h] + P[gm*4+1]*EB[Hh+h]
                   + P[gm*4+2]*EB[2*Hh+h] + P[gm*4+3]*EB[3*Hh+h];
          out[(size_t)gm * Hh + h] = sv + bt;
        }
      }
    }
  }
}

extern "C" void kernel_launch(void* const* d_in, const int* in_sizes, int n_in,
                              void* d_out, int out_size, void* d_ws, size_t ws_size,
                              hipStream_t stream) {
  const float *x  = (const float*)d_in[0],  *vol = (const float*)d_in[1];
  const float *risk = (const float*)d_in[2], *Wf = (const float*)d_in[3];
  const float *fb = (const float*)d_in[4],  *Wc = (const float*)d_in[5];
  const float *cb = (const float*)d_in[6],  *vw = (const float*)d_in[7];
  const float *vb = (const float*)d_in[8],  *rw = (const float*)d_in[9];
  const float *rb = (const float*)d_in[10], *sw = (const float*)d_in[11];
  const float *sb = (const float*)d_in[12], *We = (const float*)d_in[13];
  const float *eb = (const float*)d_in[14];

  float* out = (float*)d_out;   // fp32 output
  char* ws = (char*)d_ws;
  const size_t KB = 1024, MB = 1024 * 1024;

  float*  LP  = (float*) ws;
  bf16_t* wft = (bf16_t*)(ws + 256 * KB);
  bf16_t* wet = (bf16_t*)(ws + 256 * KB + 4 * MB);
  bf16_t* xbf = (bf16_t*)(ws + 256 * KB + 20 * MB);
  const size_t base = 256 * KB + 52 * MB;
  int Tc = TOK;
  while (Tc > 1024 && base + (size_t)Tc * F2 * sizeof(bf16_t) > ws_size) Tc >>= 1;
  bf16_t* feat = (bf16_t*)(ws + base);

  k_cvt_x <<<2048, 256, 0, stream>>>(x, xbf);
  k_tr_wf <<<dim3(F2 / 64, Hh / 64), 256, 0, stream>>>(Wf, wft);
  k_tr_we <<<dim3(F2 / 64, Hh / 64, 4), 256, 0, stream>>>(We, wet);

  for (int m0 = 0; m0 < TOK; m0 += Tc) {
    k_router_t<<<(Tc + 255) / 256, 256, 0, stream>>>(
        x, vol, risk, cb, vw, vb, rw, rb, sw, sb, LP, m0, Tc);
    k_feat_gemm<<<dim3(Tc / 128, F2 / 128), 256, 0, stream>>>(
        xbf + (size_t)m0 * Hh, wft, fb, feat);
    k_dom<<<Tc / 4, 256, 0, stream>>>(feat, Wc, LP);
    int nbm = Tc / 256;
    k_expert_gemm256<<<nbm * (NC / 256), 512, 0, stream>>>(
        feat, wet, LP, eb, out + (size_t)m0 * Hh, nbm);
  }
}

// Round 8
// 587.049 us; speedup vs baseline: 10.7667x; 1.0045x over previous
//
#include <hip/hip_runtime.h>
#include <hip/hip_bf16.h>
#include <cstdint>
#include <cstddef>

typedef __bf16 bf16_t;
typedef bf16_t bf16x8 __attribute__((ext_vector_type(8)));
typedef bf16_t bf16x4 __attribute__((ext_vector_type(4)));
typedef float  f32x4  __attribute__((ext_vector_type(4)));

#define TOK 16384   // B*S
#define Hh  1024    // hidden
#define F2  2048    // 2*H
#define NC  4096    // interleaved expert cols: h*4+d

__device__ __forceinline__ void gload_lds16(const bf16_t* g, bf16_t* lds) {
  __builtin_amdgcn_global_load_lds(
      (const __attribute__((address_space(1))) void*)g,
      (__attribute__((address_space(3))) void*)lds, 16, 0, 0);
}

// ---------------- x fp32 -> bf16 ----------------
__global__ void k_cvt_x(const float* __restrict__ x, bf16_t* __restrict__ o) {
  int i = blockIdx.x * blockDim.x + threadIdx.x;
  int stride = gridDim.x * blockDim.x;
  const float4* x4 = (const float4*)x;
  for (int j = i; j < TOK * Hh / 4; j += stride) {
    float4 v = x4[j];
    bf16x4 r = { (bf16_t)v.x, (bf16_t)v.y, (bf16_t)v.z, (bf16_t)v.w };
    *(bf16x4*)(o + (size_t)j * 4) = r;
  }
}

// ---- Wf [1024][2048] fp32 -> wft [2048][1024] bf16 (tiled transpose) ----
__global__ __launch_bounds__(256)
void k_tr_wf(const float* __restrict__ in, bf16_t* __restrict__ out) {
  __shared__ float T[64][65];
  const int f0 = blockIdx.x * 64, h0 = blockIdx.y * 64;
  const int tid = threadIdx.x;
  const int c4 = (tid & 15) * 4, r = tid >> 4;
  #pragma unroll
  for (int p = 0; p < 4; ++p) {
    int hh = p * 16 + r;
    float4 v = *(const float4*)&in[(size_t)(h0 + hh) * F2 + f0 + c4];
    T[c4 + 0][hh] = v.x; T[c4 + 1][hh] = v.y; T[c4 + 2][hh] = v.z; T[c4 + 3][hh] = v.w;
  }
  __syncthreads();
  #pragma unroll
  for (int p = 0; p < 4; ++p) {
    int ff = p * 16 + r;
    bf16x4 o = { (bf16_t)T[ff][c4 + 0], (bf16_t)T[ff][c4 + 1],
                 (bf16_t)T[ff][c4 + 2], (bf16_t)T[ff][c4 + 3] };
    *(bf16x4*)&out[(size_t)(f0 + ff) * Hh + h0 + c4] = o;
  }
}

// ---- We [4][2048][1024] fp32 -> wet [4096][2048] bf16, row cp = h*4+d ----
__global__ __launch_bounds__(256)
void k_tr_we(const float* __restrict__ in, bf16_t* __restrict__ out) {
  __shared__ float T[64][65];
  const int f0 = blockIdx.x * 64, h0 = blockIdx.y * 64, d = blockIdx.z;
  const float* ind = in + (size_t)d * F2 * Hh;
  const int tid = threadIdx.x;
  const int c4 = (tid & 15) * 4, r = tid >> 4;
  #pragma unroll
  for (int p = 0; p < 4; ++p) {
    int ff = p * 16 + r;
    float4 v = *(const float4*)&ind[(size_t)(f0 + ff) * Hh + h0 + c4];
    T[c4 + 0][ff] = v.x; T[c4 + 1][ff] = v.y; T[c4 + 2][ff] = v.z; T[c4 + 3][ff] = v.w;
  }
  __syncthreads();
  #pragma unroll
  for (int p = 0; p < 4; ++p) {
    int hh = p * 16 + r;
    bf16x4 o = { (bf16_t)T[hh][c4 + 0], (bf16_t)T[hh][c4 + 1],
                 (bf16_t)T[hh][c4 + 2], (bf16_t)T[hh][c4 + 3] };
    *(bf16x4*)&out[(size_t)((h0 + hh) * 4 + d) * F2 + f0 + c4] = o;
  }
}

// ---- per-token router logits ----
__global__ void k_router_t(const float* __restrict__ x, const float* __restrict__ vol,
                           const float* __restrict__ risk, const float* __restrict__ clsb,
                           const float* __restrict__ vw, const float* __restrict__ vb,
                           const float* __restrict__ rw, const float* __restrict__ rb,
                           const float* __restrict__ sw, const float* __restrict__ sb,
                           float* __restrict__ LP, int m0, int Tc) {
  int t = blockIdx.x * blockDim.x + threadIdx.x;
  if (t >= Tc) return;
  int s = m0 + t;
  const float4* xr = (const float4*)(x + (size_t)s * Hh);
  float sum = 0.f, sq = 0.f, mx = -1e30f;
  for (int i = 0; i < Hh / 4; ++i) {
    float4 v = xr[i];
    sum += v.x + v.y + v.z + v.w;
    sq  += v.x * v.x + v.y * v.y + v.z * v.z + v.w * v.w;
    mx = fmaxf(mx, fmaxf(fmaxf(v.x, v.y), fmaxf(v.z, v.w)));
  }
  float mean = sum * (1.0f / Hh);
  float var  = sq * (1.0f / Hh) - mean * mean;
  float sd   = sqrtf(fmaxf(var, 0.f));
  float v = vol[s], rk = risk[s];
  #pragma unroll
  for (int d = 0; d < 4; ++d) {
    float acc = clsb[d];
    #pragma unroll
    for (int k = 0; k < 8; ++k)  acc += tanhf(v  * vw[k*4+d] + vb[k*4+d]);
    #pragma unroll
    for (int k = 0; k < 8; ++k)  acc += tanhf(rk * rw[k*4+d] + rb[k*4+d]);
    #pragma unroll
    for (int k = 0; k < 12; ++k)
      acc += tanhf(mean * sw[k*4+d] + sd * sw[48 + k*4+d] + mx * sw[96 + k*4+d] + sb[k*4+d]);
    LP[t * 4 + d] = acc;
  }
}

// ---------------- GEMM 1 (MFMA 128^2, m97-style): feat = tanh(xbf @ wft^T + fb) ----------------
__global__ __launch_bounds__(256, 2)
void k_feat_gemm(const bf16_t* __restrict__ A,   // [Tc][1024]
                 const bf16_t* __restrict__ Bt,  // [2048][1024]
                 const float* __restrict__ bias, // [2048]
                 bf16_t* __restrict__ feat) {    // [Tc][2048]
  constexpr int K = Hh;
  __shared__ bf16_t As[128 * 64];
  __shared__ bf16_t Bs[128 * 64];
  const int bm = blockIdx.x, bn = blockIdx.y;
  const int tid = threadIdx.x;
  const int w = tid >> 6, l = tid & 63;
  const int wm = (w >> 1) * 64, wn = (w & 1) * 64;
  f32x4 acc[4][4] = {};
  for (int kk = 0; kk < K; kk += 64) {
    __syncthreads();
    #pragma unroll
    for (int c = 0; c < 4; ++c) {
      int q = (w * 4 + c) * 64 + l;
      int row = q >> 3, slot = q & 7;
      gload_lds16(A  + (size_t)(bm * 128 + row) * K + kk + slot * 8, &As[(w * 4 + c) * 512]);
      gload_lds16(Bt + (size_t)(bn * 128 + row) * K + kk + slot * 8, &Bs[(w * 4 + c) * 512]);
    }
    __syncthreads();
    #pragma unroll
    for (int ks = 0; ks < 2; ++ks) {
      bf16x8 av[4], bv[4];
      #pragma unroll
      for (int mi = 0; mi < 4; ++mi)
        av[mi] = *(const bf16x8*)&As[(wm + mi * 16 + (l & 15)) * 64 + ks * 32 + (l >> 4) * 8];
      #pragma unroll
      for (int ni = 0; ni < 4; ++ni)
        bv[ni] = *(const bf16x8*)&Bs[(wn + ni * 16 + (l & 15)) * 64 + ks * 32 + (l >> 4) * 8];
      #pragma unroll
      for (int mi = 0; mi < 4; ++mi)
        #pragma unroll
        for (int ni = 0; ni < 4; ++ni)
          acc[mi][ni] = __builtin_amdgcn_mfma_f32_16x16x32_bf16(av[mi], bv[ni], acc[mi][ni], 0, 0, 0);
    }
  }
  #pragma unroll
  for (int mi = 0; mi < 4; ++mi)
    #pragma unroll
    for (int ni = 0; ni < 4; ++ni) {
      int gn = bn * 128 + wn + ni * 16 + (l & 15);
      float bv = bias[gn];
      #pragma unroll
      for (int r = 0; r < 4; ++r) {
        int gm = bm * 128 + wm + mi * 16 + (l >> 4) * 4 + r;
        feat[(size_t)gm * F2 + gn] = (bf16_t)tanhf(acc[mi][ni][r] + bv);
      }
    }
}

// ---- dom logits + softmax (wave per token), in-place LP ----
__global__ void k_dom(const bf16_t* __restrict__ feat, const float* __restrict__ Wc,
                      float* __restrict__ LP) {
  int w = threadIdx.x >> 6, l = threadIdx.x & 63;
  int t = blockIdx.x * 4 + w;
  const bf16_t* fr = feat + (size_t)t * F2;
  const float4* Wc4 = (const float4*)Wc;
  float a0 = 0, a1 = 0, a2 = 0, a3 = 0;
  #pragma unroll
  for (int it = 0; it < 4; ++it) {
    int f0 = it * 512 + l * 8;
    bf16x8 v = *(const bf16x8*)(fr + f0);
    #pragma unroll
    for (int j = 0; j < 8; ++j) {
      float vf = (float)v[j];
      float4 wv = Wc4[f0 + j];
      a0 += vf * wv.x; a1 += vf * wv.y; a2 += vf * wv.z; a3 += vf * wv.w;
    }
  }
  #pragma unroll
  for (int off = 32; off; off >>= 1) {
    a0 += __shfl_xor(a0, off, 64); a1 += __shfl_xor(a1, off, 64);
    a2 += __shfl_xor(a2, off, 64); a3 += __shfl_xor(a3, off, 64);
  }
  if (l == 0) {
    float l0 = a0 + LP[t*4+0], l1 = a1 + LP[t*4+1];
    float l2 = a2 + LP[t*4+2], l3 = a3 + LP[t*4+3];
    float m = fmaxf(fmaxf(l0, l1), fmaxf(l2, l3));
    float e0 = expf(l0 - m), e1 = expf(l1 - m), e2 = expf(l2 - m), e3 = expf(l3 - m);
    float inv = 1.f / (e0 + e1 + e2 + e3);
    LP[t*4+0] = e0 * inv; LP[t*4+1] = e1 * inv; LP[t*4+2] = e2 * inv; LP[t*4+3] = e3 * inv;
  }
}

// ---------------- GEMM 2: 256x256, BK=32, 4-buffer fine-phase pipeline ----------------
// per phase: {ds_read frags | stage half-tile | barrier | setprio MFMA | barrier}
// vmcnt(8) once per K-tile; raw s_barrier (no drain).
__global__ __launch_bounds__(512, 1)
void k_expert_gemm256(const bf16_t* __restrict__ A, const bf16_t* __restrict__ Bt,
                      const float* __restrict__ P, const float* __restrict__ EB,
                      float* __restrict__ out, int nbm) {
  constexpr int K = F2, NT = K / 32;          // 64 K-tiles of 32
  __shared__ bf16_t lds[4 * 8192 * 2];        // A: 4 bufs x [256][32]; B follows
  bf16_t* ldsB = lds + 32768;
  const int tid = threadIdx.x;
  const int l = tid & 63, wid = tid >> 6;
  const int wm = wid >> 2, wn = wid & 3;      // 2 x 4 waves
  const int l15 = l & 15, lg = l >> 4;

  // XCD-bijective block swizzle (nwg = nbm*16, multiple of 8)
  const int nwg = nbm * 16, cpx = nwg >> 3;
  int swzb = (blockIdx.x & 7) * cpx + (blockIdx.x >> 3);
  const int bm = swzb % nbm, bn = swzb / nbm;

  const bf16_t* gA = A  + (size_t)(bm * 256) * K;
  const bf16_t* gB = Bt + (size_t)(bn * 256) * K;

  // staging: slot = i*512+tid; row=slot>>2, granule=slot&3; linear LDS dest,
  // inverse-swizzled global source (granule ^ row-bits-1:2; involution)
  int s_row[2], s_gx[2];
  #pragma unroll
  for (int i = 0; i < 2; ++i) {
    int slot = i * 512 + tid;
    s_row[i] = slot >> 2;
    s_gx[i]  = ((slot & 3) ^ ((s_row[i] >> 1) & 3)) << 3;  // element offset in row
  }

  #define STAGE_A(ts) do {                                                   \
    bf16_t* dst = lds + ((ts) & 3) * 8192;                                   \
    _Pragma("unroll")                                                        \
    for (int i = 0; i < 2; ++i)                                              \
      gload_lds16(gA + (size_t)s_row[i] * K + (ts) * 32 + s_gx[i],           \
                  dst + (i * 512 + tid) * 8);                                \
  } while (0)
  #define STAGE_B(ts) do {                                                   \
    bf16_t* dst = ldsB + ((ts) & 3) * 8192;                                  \
    _Pragma("unroll")                                                        \
    for (int i = 0; i < 2; ++i)                                              \
      gload_lds16(gB + (size_t)s_row[i] * K + (ts) * 32 + s_gx[i],           \
                  dst + (i * 512 + tid) * 8);                                \
  } while (0)
  #define FENCE asm volatile("" ::: "memory")

  const int cswz = ((lg ^ ((l15 >> 1) & 3)) << 3);   // swizzled read offset in row
  f32x4 acc[8][4] = {};

  // prologue: stage tiles 0,1,2; guarantee tile 0 (youngest 8 loads = tiles 1,2)
  STAGE_A(0); STAGE_B(0); STAGE_A(1); STAGE_B(1); STAGE_A(2); STAGE_B(2);
  asm volatile("s_waitcnt vmcnt(8)" ::: "memory");
  FENCE; __builtin_amdgcn_s_barrier(); FENCE;

  for (int t = 0; t < NT; ++t) {
    const bf16_t* As_ = lds  + (t & 3) * 8192;
    const bf16_t* Bs_ = ldsB + (t & 3) * 8192;
    const int ts = (t + 3) & (NT - 1);
    bf16x8 bfr[4], afr[4];

    // ---- PH0: B-frags + A-low reads | stage A(t+3) | MFMA low quadrants ----
    #pragma unroll
    for (int ni = 0; ni < 4; ++ni)
      bfr[ni] = *(const bf16x8*)&Bs_[(wn * 64 + ni * 16 + l15) * 32 + cswz];
    #pragma unroll
    for (int mi = 0; mi < 4; ++mi)
      afr[mi] = *(const bf16x8*)&As_[(wm * 128 + mi * 16 + l15) * 32 + cswz];
    STAGE_A(ts);
    FENCE; __builtin_amdgcn_s_barrier(); FENCE;
    __builtin_amdgcn_s_setprio(1);
    #pragma unroll
    for (int mi = 0; mi < 4; ++mi)
      #pragma unroll
      for (int ni = 0; ni < 4; ++ni)
        acc[mi][ni] = __builtin_amdgcn_mfma_f32_16x16x32_bf16(afr[mi], bfr[ni], acc[mi][ni], 0, 0, 0);
    __builtin_amdgcn_s_setprio(0);
    FENCE; __builtin_amdgcn_s_barrier(); FENCE;

    // ---- PH1: A-high reads | stage B(t+3) | MFMA high quadrants ----
    #pragma unroll
    for (int mi = 0; mi < 4; ++mi)
      afr[mi] = *(const bf16x8*)&As_[(wm * 128 + 64 + mi * 16 + l15) * 32 + cswz];
    STAGE_B(ts);
    FENCE; __builtin_amdgcn_s_barrier(); FENCE;
    __builtin_amdgcn_s_setprio(1);
    #pragma unroll
    for (int mi = 0; mi < 4; ++mi)
      #pragma unroll
      for (int ni = 0; ni < 4; ++ni)
        acc[4 + mi][ni] = __builtin_amdgcn_mfma_f32_16x16x32_bf16(afr[mi], bfr[ni], acc[4 + mi][ni], 0, 0, 0);
    __builtin_amdgcn_s_setprio(0);
    // guarantee tile t+1 before its reads (youngest 8 = A/B(t+2), A/B(t+3))
    asm volatile("s_waitcnt vmcnt(8)" ::: "memory");
    FENCE; __builtin_amdgcn_s_barrier(); FENCE;
  }
  asm volatile("s_waitcnt vmcnt(0)" ::: "memory");   // drain before LDS dealloc
  #undef STAGE_A
  #undef STAGE_B
  #undef FENCE

  // epilogue: gated combine (cols 4h..4h+3 in lane quad) -> fp32 out
  #pragma unroll
  for (int mi = 0; mi < 8; ++mi) {
    int gmBase = bm * 256 + wm * 128 + mi * 16 + lg * 4;
    float pr[4];
    #pragma unroll
    for (int r = 0; r < 4; ++r) pr[r] = P[(gmBase + r) * 4 + (l & 3)];
    #pragma unroll
    for (int ni = 0; ni < 4; ++ni) {
      int colp = bn * 256 + wn * 64 + ni * 16 + l15;
      int h = colp >> 2;
      #pragma unroll
      for (int r = 0; r < 4; ++r) {
        float sv = acc[mi][ni][r] * pr[r];
        sv += __shfl_xor(sv, 1, 64);
        sv += __shfl_xor(sv, 2, 64);
        if ((l & 3) == 0) {
          int gm = gmBase + r;
          float bt = P[gm*4+0]*EB[h] + P[gm*4+1]*EB[Hh+h]
                   + P[gm*4+2]*EB[2*Hh+h] + P[gm*4+3]*EB[3*Hh+h];
          out[(size_t)gm * Hh + h] = sv + bt;
        }
      }
    }
  }
}

extern "C" void kernel_launch(void* const* d_in, const int* in_sizes, int n_in,
                              void* d_out, int out_size, void* d_ws, size_t ws_size,
                              hipStream_t stream) {
  const float *x  = (const float*)d_in[0],  *vol = (const float*)d_in[1];
  const float *risk = (const float*)d_in[2], *Wf = (const float*)d_in[3];
  const float *fb = (const float*)d_in[4],  *Wc = (const float*)d_in[5];
  const float *cb = (const float*)d_in[6],  *vw = (const float*)d_in[7];
  const float *vb = (const float*)d_in[8],  *rw = (const float*)d_in[9];
  const float *rb = (const float*)d_in[10], *sw = (const float*)d_in[11];
  const float *sb = (const float*)d_in[12], *We = (const float*)d_in[13];
  const float *eb = (const float*)d_in[14];

  float* out = (float*)d_out;   // fp32 output
  char* ws = (char*)d_ws;
  const size_t KB = 1024, MB = 1024 * 1024;

  float*  LP  = (float*) ws;
  bf16_t* wft = (bf16_t*)(ws + 256 * KB);
  bf16_t* wet = (bf16_t*)(ws + 256 * KB + 4 * MB);
  bf16_t* xbf = (bf16_t*)(ws + 256 * KB + 20 * MB);
  const size_t base = 256 * KB + 52 * MB;
  int Tc = TOK;
  while (Tc > 1024 && base + (size_t)Tc * F2 * sizeof(bf16_t) > ws_size) Tc >>= 1;
  bf16_t* feat = (bf16_t*)(ws + base);

  k_cvt_x <<<2048, 256, 0, stream>>>(x, xbf);
  k_tr_wf <<<dim3(F2 / 64, Hh / 64), 256, 0, stream>>>(Wf, wft);
  k_tr_we <<<dim3(F2 / 64, Hh / 64, 4), 256, 0, stream>>>(We, wet);

  for (int m0 = 0; m0 < TOK; m0 += Tc) {
    k_router_t<<<(Tc + 255) / 256, 256, 0, stream>>>(
        x, vol, risk, cb, vw, vb, rw, rb, sw, sb, LP, m0, Tc);
    k_feat_gemm<<<dim3(Tc / 128, F2 / 128), 256, 0, stream>>>(
        xbf + (size_t)m0 * Hh, wft, fb, feat);
    k_dom<<<Tc / 4, 256, 0, stream>>>(feat, Wc, LP);
    int nbm = Tc / 256;
    k_expert_gemm256<<<nbm * (NC / 256), 512, 0, stream>>>(
        feat, wet, LP, eb, out + (size_t)m0 * Hh, nbm);
  }
}

// Round 9
// 586.761 us; speedup vs baseline: 10.7720x; 1.0005x over previous
//
#include <hip/hip_runtime.h>
#include <hip/hip_bf16.h>
#include <cstdint>
#include <cstddef>

typedef __bf16 bf16_t;
typedef bf16_t bf16x8 __attribute__((ext_vector_type(8)));
typedef bf16_t bf16x4 __attribute__((ext_vector_type(4)));
typedef float  f32x4  __attribute__((ext_vector_type(4)));

#define TOK 16384   // B*S
#define Hh  1024    // hidden
#define F2  2048    // 2*H
#define NC  4096    // interleaved expert cols: h*4+d

__device__ __forceinline__ void gload_lds16(const bf16_t* g, bf16_t* lds) {
  __builtin_amdgcn_global_load_lds(
      (const __attribute__((address_space(1))) void*)g,
      (__attribute__((address_space(3))) void*)lds, 16, 0, 0);
}

// ---------------- x fp32 -> bf16 ----------------
__global__ void k_cvt_x(const float* __restrict__ x, bf16_t* __restrict__ o) {
  int i = blockIdx.x * blockDim.x + threadIdx.x;
  int stride = gridDim.x * blockDim.x;
  const float4* x4 = (const float4*)x;
  for (int j = i; j < TOK * Hh / 4; j += stride) {
    float4 v = x4[j];
    bf16x4 r = { (bf16_t)v.x, (bf16_t)v.y, (bf16_t)v.z, (bf16_t)v.w };
    *(bf16x4*)(o + (size_t)j * 4) = r;
  }
}

// ---- Wf [1024][2048] fp32 -> wft [2048][1024] bf16 (tiled transpose) ----
__global__ __launch_bounds__(256)
void k_tr_wf(const float* __restrict__ in, bf16_t* __restrict__ out) {
  __shared__ float T[64][65];
  const int f0 = blockIdx.x * 64, h0 = blockIdx.y * 64;
  const int tid = threadIdx.x;
  const int c4 = (tid & 15) * 4, r = tid >> 4;
  #pragma unroll
  for (int p = 0; p < 4; ++p) {
    int hh = p * 16 + r;
    float4 v = *(const float4*)&in[(size_t)(h0 + hh) * F2 + f0 + c4];
    T[c4 + 0][hh] = v.x; T[c4 + 1][hh] = v.y; T[c4 + 2][hh] = v.z; T[c4 + 3][hh] = v.w;
  }
  __syncthreads();
  #pragma unroll
  for (int p = 0; p < 4; ++p) {
    int ff = p * 16 + r;
    bf16x4 o = { (bf16_t)T[ff][c4 + 0], (bf16_t)T[ff][c4 + 1],
                 (bf16_t)T[ff][c4 + 2], (bf16_t)T[ff][c4 + 3] };
    *(bf16x4*)&out[(size_t)(f0 + ff) * Hh + h0 + c4] = o;
  }
}

// ---- We [4][2048][1024] fp32 -> wet [4096][2048] bf16, row cp = h*4+d ----
__global__ __launch_bounds__(256)
void k_tr_we(const float* __restrict__ in, bf16_t* __restrict__ out) {
  __shared__ float T[64][65];
  const int f0 = blockIdx.x * 64, h0 = blockIdx.y * 64, d = blockIdx.z;
  const float* ind = in + (size_t)d * F2 * Hh;
  const int tid = threadIdx.x;
  const int c4 = (tid & 15) * 4, r = tid >> 4;
  #pragma unroll
  for (int p = 0; p < 4; ++p) {
    int ff = p * 16 + r;
    float4 v = *(const float4*)&ind[(size_t)(f0 + ff) * Hh + h0 + c4];
    T[c4 + 0][ff] = v.x; T[c4 + 1][ff] = v.y; T[c4 + 2][ff] = v.z; T[c4 + 3][ff] = v.w;
  }
  __syncthreads();
  #pragma unroll
  for (int p = 0; p < 4; ++p) {
    int hh = p * 16 + r;
    bf16x4 o = { (bf16_t)T[hh][c4 + 0], (bf16_t)T[hh][c4 + 1],
                 (bf16_t)T[hh][c4 + 2], (bf16_t)T[hh][c4 + 3] };
    *(bf16x4*)&out[(size_t)((h0 + hh) * 4 + d) * F2 + f0 + c4] = o;
  }
}

// ---- per-token router logits ----
__global__ void k_router_t(const float* __restrict__ x, const float* __restrict__ vol,
                           const float* __restrict__ risk, const float* __restrict__ clsb,
                           const float* __restrict__ vw, const float* __restrict__ vb,
                           const float* __restrict__ rw, const float* __restrict__ rb,
                           const float* __restrict__ sw, const float* __restrict__ sb,
                           float* __restrict__ LP, int m0, int Tc) {
  int t = blockIdx.x * blockDim.x + threadIdx.x;
  if (t >= Tc) return;
  int s = m0 + t;
  const float4* xr = (const float4*)(x + (size_t)s * Hh);
  float sum = 0.f, sq = 0.f, mx = -1e30f;
  for (int i = 0; i < Hh / 4; ++i) {
    float4 v = xr[i];
    sum += v.x + v.y + v.z + v.w;
    sq  += v.x * v.x + v.y * v.y + v.z * v.z + v.w * v.w;
    mx = fmaxf(mx, fmaxf(fmaxf(v.x, v.y), fmaxf(v.z, v.w)));
  }
  float mean = sum * (1.0f / Hh);
  float var  = sq * (1.0f / Hh) - mean * mean;
  float sd   = sqrtf(fmaxf(var, 0.f));
  float v = vol[s], rk = risk[s];
  #pragma unroll
  for (int d = 0; d < 4; ++d) {
    float acc = clsb[d];
    #pragma unroll
    for (int k = 0; k < 8; ++k)  acc += tanhf(v  * vw[k*4+d] + vb[k*4+d]);
    #pragma unroll
    for (int k = 0; k < 8; ++k)  acc += tanhf(rk * rw[k*4+d] + rb[k*4+d]);
    #pragma unroll
    for (int k = 0; k < 12; ++k)
      acc += tanhf(mean * sw[k*4+d] + sd * sw[48 + k*4+d] + mx * sw[96 + k*4+d] + sb[k*4+d]);
    LP[t * 4 + d] = acc;
  }
}

// ---------------- GEMM 1 (MFMA 128^2, m97-style): feat = tanh(xbf @ wft^T + fb) ----------------
__global__ __launch_bounds__(256, 2)
void k_feat_gemm(const bf16_t* __restrict__ A,   // [Tc][1024]
                 const bf16_t* __restrict__ Bt,  // [2048][1024]
                 const float* __restrict__ bias, // [2048]
                 bf16_t* __restrict__ feat) {    // [Tc][2048]
  constexpr int K = Hh;
  __shared__ bf16_t As[128 * 64];
  __shared__ bf16_t Bs[128 * 64];
  const int bm = blockIdx.x, bn = blockIdx.y;
  const int tid = threadIdx.x;
  const int w = tid >> 6, l = tid & 63;
  const int wm = (w >> 1) * 64, wn = (w & 1) * 64;
  f32x4 acc[4][4] = {};
  for (int kk = 0; kk < K; kk += 64) {
    __syncthreads();
    #pragma unroll
    for (int c = 0; c < 4; ++c) {
      int q = (w * 4 + c) * 64 + l;
      int row = q >> 3, slot = q & 7;
      gload_lds16(A  + (size_t)(bm * 128 + row) * K + kk + slot * 8, &As[(w * 4 + c) * 512]);
      gload_lds16(Bt + (size_t)(bn * 128 + row) * K + kk + slot * 8, &Bs[(w * 4 + c) * 512]);
    }
    __syncthreads();
    #pragma unroll
    for (int ks = 0; ks < 2; ++ks) {
      bf16x8 av[4], bv[4];
      #pragma unroll
      for (int mi = 0; mi < 4; ++mi)
        av[mi] = *(const bf16x8*)&As[(wm + mi * 16 + (l & 15)) * 64 + ks * 32 + (l >> 4) * 8];
      #pragma unroll
      for (int ni = 0; ni < 4; ++ni)
        bv[ni] = *(const bf16x8*)&Bs[(wn + ni * 16 + (l & 15)) * 64 + ks * 32 + (l >> 4) * 8];
      #pragma unroll
      for (int mi = 0; mi < 4; ++mi)
        #pragma unroll
        for (int ni = 0; ni < 4; ++ni)
          acc[mi][ni] = __builtin_amdgcn_mfma_f32_16x16x32_bf16(av[mi], bv[ni], acc[mi][ni], 0, 0, 0);
    }
  }
  #pragma unroll
  for (int mi = 0; mi < 4; ++mi)
    #pragma unroll
    for (int ni = 0; ni < 4; ++ni) {
      int gn = bn * 128 + wn + ni * 16 + (l & 15);
      float bv = bias[gn];
      #pragma unroll
      for (int r = 0; r < 4; ++r) {
        int gm = bm * 128 + wm + mi * 16 + (l >> 4) * 4 + r;
        feat[(size_t)gm * F2 + gn] = (bf16_t)tanhf(acc[mi][ni][r] + bv);
      }
    }
}

// ---- dom logits + softmax (wave per token), in-place LP ----
__global__ void k_dom(const bf16_t* __restrict__ feat, const float* __restrict__ Wc,
                      float* __restrict__ LP) {
  int w = threadIdx.x >> 6, l = threadIdx.x & 63;
  int t = blockIdx.x * 4 + w;
  const bf16_t* fr = feat + (size_t)t * F2;
  const float4* Wc4 = (const float4*)Wc;
  float a0 = 0, a1 = 0, a2 = 0, a3 = 0;
  #pragma unroll
  for (int it = 0; it < 4; ++it) {
    int f0 = it * 512 + l * 8;
    bf16x8 v = *(const bf16x8*)(fr + f0);
    #pragma unroll
    for (int j = 0; j < 8; ++j) {
      float vf = (float)v[j];
      float4 wv = Wc4[f0 + j];
      a0 += vf * wv.x; a1 += vf * wv.y; a2 += vf * wv.z; a3 += vf * wv.w;
    }
  }
  #pragma unroll
  for (int off = 32; off; off >>= 1) {
    a0 += __shfl_xor(a0, off, 64); a1 += __shfl_xor(a1, off, 64);
    a2 += __shfl_xor(a2, off, 64); a3 += __shfl_xor(a3, off, 64);
  }
  if (l == 0) {
    float l0 = a0 + LP[t*4+0], l1 = a1 + LP[t*4+1];
    float l2 = a2 + LP[t*4+2], l3 = a3 + LP[t*4+3];
    float m = fmaxf(fmaxf(l0, l1), fmaxf(l2, l3));
    float e0 = expf(l0 - m), e1 = expf(l1 - m), e2 = expf(l2 - m), e3 = expf(l3 - m);
    float inv = 1.f / (e0 + e1 + e2 + e3);
    LP[t*4+0] = e0 * inv; LP[t*4+1] = e1 * inv; LP[t*4+2] = e2 * inv; LP[t*4+3] = e3 * inv;
  }
}

// ---------------- GEMM 2: 256x256, BK=32, 4-buffer, SINGLE-barrier pipelined tile ----------------
// per tile: STAGE(t+3) issue | 12 ds_reads(t) | 32 MFMA (overlapped via lgkm) |
//           lgkmcnt(0) [WAR fence] | counted vmcnt | barrier
__global__ __launch_bounds__(512, 1)
void k_expert_gemm256(const bf16_t* __restrict__ A, const bf16_t* __restrict__ Bt,
                      const float* __restrict__ P, const float* __restrict__ EB,
                      float* __restrict__ out, int nbm) {
  constexpr int K = F2, NT = K / 32;          // 64 K-tiles of 32
  __shared__ bf16_t lds[4 * 8192 * 2];        // A: 4 bufs x [256][32]; B follows
  bf16_t* ldsB = lds + 32768;
  const int tid = threadIdx.x;
  const int l = tid & 63, wid = tid >> 6;
  const int wm = wid >> 2, wn = wid & 3;      // 2 x 4 waves
  const int l15 = l & 15, lg = l >> 4;

  // XCD-bijective block swizzle (nwg = nbm*16, multiple of 8)
  const int nwg = nbm * 16, cpx = nwg >> 3;
  int swzb = (blockIdx.x & 7) * cpx + (blockIdx.x >> 3);
  const int bm = swzb % nbm, bn = swzb / nbm;

  const bf16_t* gA = A  + (size_t)(bm * 256) * K;
  const bf16_t* gB = Bt + (size_t)(bn * 256) * K;

  // staging: slot = i*512+tid; row=slot>>2, granule=slot&3; linear LDS dest,
  // inverse-swizzled global source (granule ^ row-bits-1:2; involution)
  int s_row[2], s_gx[2];
  #pragma unroll
  for (int i = 0; i < 2; ++i) {
    int slot = i * 512 + tid;
    s_row[i] = slot >> 2;
    s_gx[i]  = ((slot & 3) ^ ((s_row[i] >> 1) & 3)) << 3;
  }

  #define STAGE(ts) do {                                                     \
    bf16_t* dstA = lds  + ((ts) & 3) * 8192;                                 \
    bf16_t* dstB = ldsB + ((ts) & 3) * 8192;                                 \
    _Pragma("unroll")                                                        \
    for (int i = 0; i < 2; ++i)                                              \
      gload_lds16(gA + (size_t)s_row[i] * K + (ts) * 32 + s_gx[i],           \
                  dstA + (i * 512 + tid) * 8);                               \
    _Pragma("unroll")                                                        \
    for (int i = 0; i < 2; ++i)                                              \
      gload_lds16(gB + (size_t)s_row[i] * K + (ts) * 32 + s_gx[i],           \
                  dstB + (i * 512 + tid) * 8);                               \
  } while (0)
  #define FENCE asm volatile("" ::: "memory")

  const int cswz = ((lg ^ ((l15 >> 1) & 3)) << 3);   // swizzled read offset in row
  f32x4 acc[8][4] = {};

  // prologue: stage tiles 0,1,2 (12 loads/wave); tile 0 landed when <=8 outstanding
  STAGE(0); STAGE(1); STAGE(2);
  asm volatile("s_waitcnt vmcnt(8)" ::: "memory");
  FENCE; __builtin_amdgcn_s_barrier(); FENCE;

  for (int t = 0; t < NT; ++t) {
    const bf16_t* As_ = lds  + (t & 3) * 8192;
    const bf16_t* Bs_ = ldsB + (t & 3) * 8192;

    if (t + 3 < NT) STAGE(t + 3);   // issue-early; lands whenever (T14)

    // 12 ds_reads for tile t (bfr first so ni-cluster 0 depends on reads 1..5)
    bf16x8 bfr[4], al[4], ah[4];
    bfr[0] = *(const bf16x8*)&Bs_[(wn * 64 + 0 * 16 + l15) * 32 + cswz];
    #pragma unroll
    for (int mi = 0; mi < 4; ++mi)
      al[mi] = *(const bf16x8*)&As_[(wm * 128 + mi * 16 + l15) * 32 + cswz];
    #pragma unroll
    for (int ni = 1; ni < 4; ++ni)
      bfr[ni] = *(const bf16x8*)&Bs_[(wn * 64 + ni * 16 + l15) * 32 + cswz];
    #pragma unroll
    for (int mi = 0; mi < 4; ++mi)
      ah[mi] = *(const bf16x8*)&As_[(wm * 128 + 64 + mi * 16 + l15) * 32 + cswz];

    // 32 MFMA; fine-grained lgkm waits let LDS service late reads during compute
    __builtin_amdgcn_s_setprio(1);
    #pragma unroll
    for (int ni = 0; ni < 4; ++ni)
      #pragma unroll
      for (int mi = 0; mi < 4; ++mi)
        acc[mi][ni] = __builtin_amdgcn_mfma_f32_16x16x32_bf16(al[mi], bfr[ni], acc[mi][ni], 0, 0, 0);
    #pragma unroll
    for (int ni = 0; ni < 4; ++ni)
      #pragma unroll
      for (int mi = 0; mi < 4; ++mi)
        acc[4 + mi][ni] = __builtin_amdgcn_mfma_f32_16x16x32_bf16(ah[mi], bfr[ni], acc[4 + mi][ni], 0, 0, 0);
    __builtin_amdgcn_s_setprio(0);

    // WAR fence: my slot-(t) reads all serviced before I pass the barrier
    asm volatile("s_waitcnt lgkmcnt(0)" ::: "memory");
    // counted vmem wait: guarantee tile t+1 landed for next iter's reads
    if (t < NT - 3)       asm volatile("s_waitcnt vmcnt(8)" ::: "memory");
    else if (t == NT - 3) asm volatile("s_waitcnt vmcnt(4)" ::: "memory");
    else                  asm volatile("s_waitcnt vmcnt(0)" ::: "memory");
    FENCE; __builtin_amdgcn_s_barrier(); FENCE;
  }
  #undef STAGE
  #undef FENCE

  // epilogue: gated combine (cols 4h..4h+3 in lane quad) -> fp32 out
  #pragma unroll
  for (int mi = 0; mi < 8; ++mi) {
    int gmBase = bm * 256 + wm * 128 + mi * 16 + lg * 4;
    float pr[4];
    #pragma unroll
    for (int r = 0; r < 4; ++r) pr[r] = P[(gmBase + r) * 4 + (l & 3)];
    #pragma unroll
    for (int ni = 0; ni < 4; ++ni) {
      int colp = bn * 256 + wn * 64 + ni * 16 + l15;
      int h = colp >> 2;
      #pragma unroll
      for (int r = 0; r < 4; ++r) {
        float sv = acc[mi][ni][r] * pr[r];
        sv += __shfl_xor(sv, 1, 64);
        sv += __shfl_xor(sv, 2, 64);
        if ((l & 3) == 0) {
          int gm = gmBase + r;
          float bt = P[gm*4+0]*EB[h] + P[gm*4+1]*EB[Hh+h]
                   + P[gm*4+2]*EB[2*Hh+h] + P[gm*4+3]*EB[3*Hh+h];
          out[(size_t)gm * Hh + h] = sv + bt;
        }
      }
    }
  }
}

extern "C" void kernel_launch(void* const* d_in, const int* in_sizes, int n_in,
                              void* d_out, int out_size, void* d_ws, size_t ws_size,
                              hipStream_t stream) {
  const float *x  = (const float*)d_in[0],  *vol = (const float*)d_in[1];
  const float *risk = (const float*)d_in[2], *Wf = (const float*)d_in[3];
  const float *fb = (const float*)d_in[4],  *Wc = (const float*)d_in[5];
  const float *cb = (const float*)d_in[6],  *vw = (const float*)d_in[7];
  const float *vb = (const float*)d_in[8],  *rw = (const float*)d_in[9];
  const float *rb = (const float*)d_in[10], *sw = (const float*)d_in[11];
  const float *sb = (const float*)d_in[12], *We = (const float*)d_in[13];
  const float *eb = (const float*)d_in[14];

  float* out = (float*)d_out;   // fp32 output
  char* ws = (char*)d_ws;
  const size_t KB = 1024, MB = 1024 * 1024;

  float*  LP  = (float*) ws;
  bf16_t* wft = (bf16_t*)(ws + 256 * KB);
  bf16_t* wet = (bf16_t*)(ws + 256 * KB + 4 * MB);
  bf16_t* xbf = (bf16_t*)(ws + 256 * KB + 20 * MB);
  const size_t base = 256 * KB + 52 * MB;
  int Tc = TOK;
  while (Tc > 1024 && base + (size_t)Tc * F2 * sizeof(bf16_t) > ws_size) Tc >>= 1;
  bf16_t* feat = (bf16_t*)(ws + base);

  k_cvt_x <<<2048, 256, 0, stream>>>(x, xbf);
  k_tr_wf <<<dim3(F2 / 64, Hh / 64), 256, 0, stream>>>(Wf, wft);
  k_tr_we <<<dim3(F2 / 64, Hh / 64, 4), 256, 0, stream>>>(We, wet);

  for (int m0 = 0; m0 < TOK; m0 += Tc) {
    k_router_t<<<(Tc + 255) / 256, 256, 0, stream>>>(
        x, vol, risk, cb, vw, vb, rw, rb, sw, sb, LP, m0, Tc);
    k_feat_gemm<<<dim3(Tc / 128, F2 / 128), 256, 0, stream>>>(
        xbf + (size_t)m0 * Hh, wft, fb, feat);
    k_dom<<<Tc / 4, 256, 0, stream>>>(feat, Wc, LP);
    int nbm = Tc / 256;
    k_expert_gemm256<<<nbm * (NC / 256), 512, 0, stream>>>(
        feat, wet, LP, eb, out + (size_t)m0 * Hh, nbm);
  }
}

// Round 10
// 582.465 us; speedup vs baseline: 10.8514x; 1.0074x over previous
//
#include <hip/hip_runtime.h>
#include <hip/hip_bf16.h>
#include <cstdint>
#include <cstddef>

typedef __bf16 bf16_t;
typedef bf16_t bf16x8 __attribute__((ext_vector_type(8)));
typedef bf16_t bf16x4 __attribute__((ext_vector_type(4)));
typedef float  f32x4  __attribute__((ext_vector_type(4)));

#define TOK 16384   // B*S
#define Hh  1024    // hidden
#define F2  2048    // 2*H
#define NC  4096    // interleaved expert cols: h*4+d

__device__ __forceinline__ void gload_lds16(const bf16_t* g, bf16_t* lds) {
  __builtin_amdgcn_global_load_lds(
      (const __attribute__((address_space(1))) void*)g,
      (__attribute__((address_space(3))) void*)lds, 16, 0, 0);
}

// ---------------- x fp32 -> bf16 ----------------
__global__ void k_cvt_x(const float* __restrict__ x, bf16_t* __restrict__ o) {
  int i = blockIdx.x * blockDim.x + threadIdx.x;
  int stride = gridDim.x * blockDim.x;
  const float4* x4 = (const float4*)x;
  for (int j = i; j < TOK * Hh / 4; j += stride) {
    float4 v = x4[j];
    bf16x4 r = { (bf16_t)v.x, (bf16_t)v.y, (bf16_t)v.z, (bf16_t)v.w };
    *(bf16x4*)(o + (size_t)j * 4) = r;
  }
}

// ---- Wf [1024][2048] fp32 -> wft [2048][1024] bf16 (tiled transpose) ----
__global__ __launch_bounds__(256)
void k_tr_wf(const float* __restrict__ in, bf16_t* __restrict__ out) {
  __shared__ float T[64][65];
  const int f0 = blockIdx.x * 64, h0 = blockIdx.y * 64;
  const int tid = threadIdx.x;
  const int c4 = (tid & 15) * 4, r = tid >> 4;
  #pragma unroll
  for (int p = 0; p < 4; ++p) {
    int hh = p * 16 + r;
    float4 v = *(const float4*)&in[(size_t)(h0 + hh) * F2 + f0 + c4];
    T[c4 + 0][hh] = v.x; T[c4 + 1][hh] = v.y; T[c4 + 2][hh] = v.z; T[c4 + 3][hh] = v.w;
  }
  __syncthreads();
  #pragma unroll
  for (int p = 0; p < 4; ++p) {
    int ff = p * 16 + r;
    bf16x4 o = { (bf16_t)T[ff][c4 + 0], (bf16_t)T[ff][c4 + 1],
                 (bf16_t)T[ff][c4 + 2], (bf16_t)T[ff][c4 + 3] };
    *(bf16x4*)&out[(size_t)(f0 + ff) * Hh + h0 + c4] = o;
  }
}

// ---- We [4][2048][1024] fp32 -> wet [4096][2048] bf16, row cp = h*4+d ----
__global__ __launch_bounds__(256)
void k_tr_we(const float* __restrict__ in, bf16_t* __restrict__ out) {
  __shared__ float T[64][65];
  const int f0 = blockIdx.x * 64, h0 = blockIdx.y * 64, d = blockIdx.z;
  const float* ind = in + (size_t)d * F2 * Hh;
  const int tid = threadIdx.x;
  const int c4 = (tid & 15) * 4, r = tid >> 4;
  #pragma unroll
  for (int p = 0; p < 4; ++p) {
    int ff = p * 16 + r;
    float4 v = *(const float4*)&ind[(size_t)(f0 + ff) * Hh + h0 + c4];
    T[c4 + 0][ff] = v.x; T[c4 + 1][ff] = v.y; T[c4 + 2][ff] = v.z; T[c4 + 3][ff] = v.w;
  }
  __syncthreads();
  #pragma unroll
  for (int p = 0; p < 4; ++p) {
    int hh = p * 16 + r;
    bf16x4 o = { (bf16_t)T[hh][c4 + 0], (bf16_t)T[hh][c4 + 1],
                 (bf16_t)T[hh][c4 + 2], (bf16_t)T[hh][c4 + 3] };
    *(bf16x4*)&out[(size_t)((h0 + hh) * 4 + d) * F2 + f0 + c4] = o;
  }
}

// ---- per-token router logits ----
__global__ void k_router_t(const float* __restrict__ x, const float* __restrict__ vol,
                           const float* __restrict__ risk, const float* __restrict__ clsb,
                           const float* __restrict__ vw, const float* __restrict__ vb,
                           const float* __restrict__ rw, const float* __restrict__ rb,
                           const float* __restrict__ sw, const float* __restrict__ sb,
                           float* __restrict__ LP, int m0, int Tc) {
  int t = blockIdx.x * blockDim.x + threadIdx.x;
  if (t >= Tc) return;
  int s = m0 + t;
  const float4* xr = (const float4*)(x + (size_t)s * Hh);
  float sum = 0.f, sq = 0.f, mx = -1e30f;
  for (int i = 0; i < Hh / 4; ++i) {
    float4 v = xr[i];
    sum += v.x + v.y + v.z + v.w;
    sq  += v.x * v.x + v.y * v.y + v.z * v.z + v.w * v.w;
    mx = fmaxf(mx, fmaxf(fmaxf(v.x, v.y), fmaxf(v.z, v.w)));
  }
  float mean = sum * (1.0f / Hh);
  float var  = sq * (1.0f / Hh) - mean * mean;
  float sd   = sqrtf(fmaxf(var, 0.f));
  float v = vol[s], rk = risk[s];
  #pragma unroll
  for (int d = 0; d < 4; ++d) {
    float acc = clsb[d];
    #pragma unroll
    for (int k = 0; k < 8; ++k)  acc += tanhf(v  * vw[k*4+d] + vb[k*4+d]);
    #pragma unroll
    for (int k = 0; k < 8; ++k)  acc += tanhf(rk * rw[k*4+d] + rb[k*4+d]);
    #pragma unroll
    for (int k = 0; k < 12; ++k)
      acc += tanhf(mean * sw[k*4+d] + sd * sw[48 + k*4+d] + mx * sw[96 + k*4+d] + sb[k*4+d]);
    LP[t * 4 + d] = acc;
  }
}

// ---------------- GEMM 1 (MFMA 128^2, m97-style): feat = tanh(xbf @ wft^T + fb) ----------------
__global__ __launch_bounds__(256, 2)
void k_feat_gemm(const bf16_t* __restrict__ A,   // [Tc][1024]
                 const bf16_t* __restrict__ Bt,  // [2048][1024]
                 const float* __restrict__ bias, // [2048]
                 bf16_t* __restrict__ feat) {    // [Tc][2048]
  constexpr int K = Hh;
  __shared__ bf16_t As[128 * 64];
  __shared__ bf16_t Bs[128 * 64];
  const int bm = blockIdx.x, bn = blockIdx.y;
  const int tid = threadIdx.x;
  const int w = tid >> 6, l = tid & 63;
  const int wm = (w >> 1) * 64, wn = (w & 1) * 64;
  f32x4 acc[4][4] = {};
  for (int kk = 0; kk < K; kk += 64) {
    __syncthreads();
    #pragma unroll
    for (int c = 0; c < 4; ++c) {
      int q = (w * 4 + c) * 64 + l;
      int row = q >> 3, slot = q & 7;
      gload_lds16(A  + (size_t)(bm * 128 + row) * K + kk + slot * 8, &As[(w * 4 + c) * 512]);
      gload_lds16(Bt + (size_t)(bn * 128 + row) * K + kk + slot * 8, &Bs[(w * 4 + c) * 512]);
    }
    __syncthreads();
    #pragma unroll
    for (int ks = 0; ks < 2; ++ks) {
      bf16x8 av[4], bv[4];
      #pragma unroll
      for (int mi = 0; mi < 4; ++mi)
        av[mi] = *(const bf16x8*)&As[(wm + mi * 16 + (l & 15)) * 64 + ks * 32 + (l >> 4) * 8];
      #pragma unroll
      for (int ni = 0; ni < 4; ++ni)
        bv[ni] = *(const bf16x8*)&Bs[(wn + ni * 16 + (l & 15)) * 64 + ks * 32 + (l >> 4) * 8];
      #pragma unroll
      for (int mi = 0; mi < 4; ++mi)
        #pragma unroll
        for (int ni = 0; ni < 4; ++ni)
          acc[mi][ni] = __builtin_amdgcn_mfma_f32_16x16x32_bf16(av[mi], bv[ni], acc[mi][ni], 0, 0, 0);
    }
  }
  #pragma unroll
  for (int mi = 0; mi < 4; ++mi)
    #pragma unroll
    for (int ni = 0; ni < 4; ++ni) {
      int gn = bn * 128 + wn + ni * 16 + (l & 15);
      float bv = bias[gn];
      #pragma unroll
      for (int r = 0; r < 4; ++r) {
        int gm = bm * 128 + wm + mi * 16 + (l >> 4) * 4 + r;
        feat[(size_t)gm * F2 + gn] = (bf16_t)tanhf(acc[mi][ni][r] + bv);
      }
    }
}

// ---- dom logits + softmax (wave per token), in-place LP ----
__global__ void k_dom(const bf16_t* __restrict__ feat, const float* __restrict__ Wc,
                      float* __restrict__ LP) {
  int w = threadIdx.x >> 6, l = threadIdx.x & 63;
  int t = blockIdx.x * 4 + w;
  const bf16_t* fr = feat + (size_t)t * F2;
  const float4* Wc4 = (const float4*)Wc;
  float a0 = 0, a1 = 0, a2 = 0, a3 = 0;
  #pragma unroll
  for (int it = 0; it < 4; ++it) {
    int f0 = it * 512 + l * 8;
    bf16x8 v = *(const bf16x8*)(fr + f0);
    #pragma unroll
    for (int j = 0; j < 8; ++j) {
      float vf = (float)v[j];
      float4 wv = Wc4[f0 + j];
      a0 += vf * wv.x; a1 += vf * wv.y; a2 += vf * wv.z; a3 += vf * wv.w;
    }
  }
  #pragma unroll
  for (int off = 32; off; off >>= 1) {
    a0 += __shfl_xor(a0, off, 64); a1 += __shfl_xor(a1, off, 64);
    a2 += __shfl_xor(a2, off, 64); a3 += __shfl_xor(a3, off, 64);
  }
  if (l == 0) {
    float l0 = a0 + LP[t*4+0], l1 = a1 + LP[t*4+1];
    float l2 = a2 + LP[t*4+2], l3 = a3 + LP[t*4+3];
    float m = fmaxf(fmaxf(l0, l1), fmaxf(l2, l3));
    float e0 = expf(l0 - m), e1 = expf(l1 - m), e2 = expf(l2 - m), e3 = expf(l3 - m);
    float inv = 1.f / (e0 + e1 + e2 + e3);
    LP[t*4+0] = e0 * inv; LP[t*4+1] = e1 * inv; LP[t*4+2] = e2 * inv; LP[t*4+3] = e3 * inv;
  }
}

// ---------------- GEMM 2: 256x256, BK=32, 4-buffer, register read-ahead pipeline ----------------
// per tile t: STAGE(t+3) | ah-reads(t) | bfr/al-reads(t+1) into ALT reg set |
//             16 MFMA (zero-dep) + 16 MFMA (ah-gated) | vmcnt(4) | barrier
__global__ __launch_bounds__(512, 1)
void k_expert_gemm256(const bf16_t* __restrict__ A, const bf16_t* __restrict__ Bt,
                      const float* __restrict__ P, const float* __restrict__ EB,
                      float* __restrict__ out, int nbm) {
  constexpr int K = F2, NT = K / 32;          // 64 K-tiles of 32
  __shared__ bf16_t lds[4 * 8192 * 2];        // A: 4 bufs x [256][32]; B follows
  bf16_t* ldsB = lds + 32768;
  const int tid = threadIdx.x;
  const int l = tid & 63, wid = tid >> 6;
  const int wm = wid >> 2, wn = wid & 3;      // 2 x 4 waves
  const int l15 = l & 15, lg = l >> 4;

  // XCD-bijective block swizzle (nwg = nbm*16, multiple of 8)
  const int nwg = nbm * 16, cpx = nwg >> 3;
  int swzb = (blockIdx.x & 7) * cpx + (blockIdx.x >> 3);
  const int bm = swzb % nbm, bn = swzb / nbm;

  const bf16_t* gA = A  + (size_t)(bm * 256) * K;
  const bf16_t* gB = Bt + (size_t)(bn * 256) * K;

  // staging: slot = i*512+tid; row=slot>>2, granule=slot&3; linear LDS dest,
  // inverse-swizzled global source (granule ^ row-bits-1:2; involution)
  int s_row[2], s_gx[2];
  #pragma unroll
  for (int i = 0; i < 2; ++i) {
    int slot = i * 512 + tid;
    s_row[i] = slot >> 2;
    s_gx[i]  = ((slot & 3) ^ ((s_row[i] >> 1) & 3)) << 3;
  }

  #define STAGE(ts) do {                                                     \
    bf16_t* dstA = lds  + ((ts) & 3) * 8192;                                 \
    bf16_t* dstB = ldsB + ((ts) & 3) * 8192;                                 \
    _Pragma("unroll")                                                        \
    for (int i = 0; i < 2; ++i)                                              \
      gload_lds16(gA + (size_t)s_row[i] * K + (ts) * 32 + s_gx[i],           \
                  dstA + (i * 512 + tid) * 8);                               \
    _Pragma("unroll")                                                        \
    for (int i = 0; i < 2; ++i)                                              \
      gload_lds16(gB + (size_t)s_row[i] * K + (ts) * 32 + s_gx[i],           \
                  dstB + (i * 512 + tid) * 8);                               \
  } while (0)
  #define FENCE asm volatile("" ::: "memory")

  const int cswz = ((lg ^ ((l15 >> 1) & 3)) << 3);   // swizzled read offset in row
  f32x4 acc[8][4] = {};
  bf16x8 bfrE[4], alE[4], bfrO[4], alO[4], ah[4];

  // prologue: stage tiles 0,1,2; vmcnt(4) -> tiles 0 AND 1 landed; read set E(0)
  STAGE(0); STAGE(1); STAGE(2);
  asm volatile("s_waitcnt vmcnt(4)" ::: "memory");
  FENCE; __builtin_amdgcn_s_barrier(); FENCE;
  #pragma unroll
  for (int ni = 0; ni < 4; ++ni)
    bfrE[ni] = *(const bf16x8*)&ldsB[(wn * 64 + ni * 16 + l15) * 32 + cswz];
  #pragma unroll
  for (int mi = 0; mi < 4; ++mi)
    alE[mi] = *(const bf16x8*)&lds[(wm * 128 + mi * 16 + l15) * 32 + cswz];

  // TILE_BODY: cur set (bfrC,alC) computes tile T; next set (bfrN,alN) prefetched for T+1
  #define TILE_BODY(T, bfrC, alC, bfrN, alN, DOSTAGE, DOREADS, VMN)            \
  {                                                                            \
    const bf16_t* AsC = lds  + ((T) & 3) * 8192;                               \
    const bf16_t* BsC = ldsB + ((T) & 3) * 8192;                               \
    const bf16_t* AsN = lds  + (((T) + 1) & 3) * 8192;                         \
    const bf16_t* BsN = ldsB + (((T) + 1) & 3) * 8192;                         \
    if (DOSTAGE) STAGE((T) + 3);                                               \
    _Pragma("unroll")                                                          \
    for (int mi = 0; mi < 4; ++mi)                                             \
      ah[mi] = *(const bf16x8*)&AsC[(wm * 128 + 64 + mi * 16 + l15) * 32 + cswz]; \
    if (DOREADS) {                                                             \
      _Pragma("unroll")                                                        \
      for (int ni = 0; ni < 4; ++ni)                                           \
        bfrN[ni] = *(const bf16x8*)&BsN[(wn * 64 + ni * 16 + l15) * 32 + cswz];\
      _Pragma("unroll")                                                        \
      for (int mi = 0; mi < 4; ++mi)                                           \
        alN[mi] = *(const bf16x8*)&AsN[(wm * 128 + mi * 16 + l15) * 32 + cswz];\
    }                                                                          \
    __builtin_amdgcn_s_setprio(1);                                             \
    _Pragma("unroll")                                                          \
    for (int ni = 0; ni < 4; ++ni)                                             \
      _Pragma("unroll")                                                        \
      for (int mi = 0; mi < 4; ++mi)                                           \
        acc[mi][ni] = __builtin_amdgcn_mfma_f32_16x16x32_bf16(                 \
            alC[mi], bfrC[ni], acc[mi][ni], 0, 0, 0);                          \
    _Pragma("unroll")                                                          \
    for (int ni = 0; ni < 4; ++ni)                                             \
      _Pragma("unroll")                                                        \
      for (int mi = 0; mi < 4; ++mi)                                           \
        acc[4 + mi][ni] = __builtin_amdgcn_mfma_f32_16x16x32_bf16(             \
            ah[mi], bfrC[ni], acc[4 + mi][ni], 0, 0, 0);                       \
    __builtin_amdgcn_s_setprio(0);                                             \
    asm volatile("s_waitcnt vmcnt(" #VMN ")" ::: "memory");                    \
    FENCE; __builtin_amdgcn_s_barrier(); FENCE;                                \
  }

  // main loop: tiles 0..59, branch-free body (stage & reads always valid)
  for (int tp = 0; tp < NT - 4; tp += 2) {
    TILE_BODY(tp,     bfrE, alE, bfrO, alO, true, true, 4);
    TILE_BODY(tp + 1, bfrO, alO, bfrE, alE, true, true, 4);
  }
  // tail: tiles 60..63 peeled
  TILE_BODY(NT - 4, bfrE, alE, bfrO, alO, true,  true,  4);
  TILE_BODY(NT - 3, bfrO, alO, bfrE, alE, false, true,  0);
  TILE_BODY(NT - 2, bfrE, alE, bfrO, alO, false, true,  0);
  TILE_BODY(NT - 1, bfrO, alO, bfrE, alE, false, false, 0);
  #undef TILE_BODY
  #undef STAGE
  #undef FENCE

  // epilogue: gated combine (cols 4h..4h+3 in lane quad) -> fp32 out
  #pragma unroll
  for (int mi = 0; mi < 8; ++mi) {
    int gmBase = bm * 256 + wm * 128 + mi * 16 + lg * 4;
    float pr[4];
    #pragma unroll
    for (int r = 0; r < 4; ++r) pr[r] = P[(gmBase + r) * 4 + (l & 3)];
    #pragma unroll
    for (int ni = 0; ni < 4; ++ni) {
      int colp = bn * 256 + wn * 64 + ni * 16 + l15;
      int h = colp >> 2;
      #pragma unroll
      for (int r = 0; r < 4; ++r) {
        float sv = acc[mi][ni][r] * pr[r];
        sv += __shfl_xor(sv, 1, 64);
        sv += __shfl_xor(sv, 2, 64);
        if ((l & 3) == 0) {
          int gm = gmBase + r;
          float bt = P[gm*4+0]*EB[h] + P[gm*4+1]*EB[Hh+h]
                   + P[gm*4+2]*EB[2*Hh+h] + P[gm*4+3]*EB[3*Hh+h];
          out[(size_t)gm * Hh + h] = sv + bt;
        }
      }
    }
  }
}

extern "C" void kernel_launch(void* const* d_in, const int* in_sizes, int n_in,
                              void* d_out, int out_size, void* d_ws, size_t ws_size,
                              hipStream_t stream) {
  const float *x  = (const float*)d_in[0],  *vol = (const float*)d_in[1];
  const float *risk = (const float*)d_in[2], *Wf = (const float*)d_in[3];
  const float *fb = (const float*)d_in[4],  *Wc = (const float*)d_in[5];
  const float *cb = (const float*)d_in[6],  *vw = (const float*)d_in[7];
  const float *vb = (const float*)d_in[8],  *rw = (const float*)d_in[9];
  const float *rb = (const float*)d_in[10], *sw = (const float*)d_in[11];
  const float *sb = (const float*)d_in[12], *We = (const float*)d_in[13];
  const float *eb = (const float*)d_in[14];

  float* out = (float*)d_out;   // fp32 output
  char* ws = (char*)d_ws;
  const size_t KB = 1024, MB = 1024 * 1024;

  float*  LP  = (float*) ws;
  bf16_t* wft = (bf16_t*)(ws + 256 * KB);
  bf16_t* wet = (bf16_t*)(ws + 256 * KB + 4 * MB);
  bf16_t* xbf = (bf16_t*)(ws + 256 * KB + 20 * MB);
  const size_t base = 256 * KB + 52 * MB;
  int Tc = TOK;
  while (Tc > 1024 && base + (size_t)Tc * F2 * sizeof(bf16_t) > ws_size) Tc >>= 1;
  bf16_t* feat = (bf16_t*)(ws + base);

  k_cvt_x <<<2048, 256, 0, stream>>>(x, xbf);
  k_tr_wf <<<dim3(F2 / 64, Hh / 64), 256, 0, stream>>>(Wf, wft);
  k_tr_we <<<dim3(F2 / 64, Hh / 64, 4), 256, 0, stream>>>(We, wet);

  for (int m0 = 0; m0 < TOK; m0 += Tc) {
    k_router_t<<<(Tc + 255) / 256, 256, 0, stream>>>(
        x, vol, risk, cb, vw, vb, rw, rb, sw, sb, LP, m0, Tc);
    k_feat_gemm<<<dim3(Tc / 128, F2 / 128), 256, 0, stream>>>(
        xbf + (size_t)m0 * Hh, wft, fb, feat);
    k_dom<<<Tc / 4, 256, 0, stream>>>(feat, Wc, LP);
    int nbm = Tc / 256;
    k_expert_gemm256<<<nbm * (NC / 256), 512, 0, stream>>>(
        feat, wet, LP, eb, out + (size_t)m0 * Hh, nbm);
  }
}

// Round 11
// 582.282 us; speedup vs baseline: 10.8549x; 1.0003x over previous
//
#include <hip/hip_runtime.h>
#include <hip/hip_bf16.h>
#include <cstdint>
#include <cstddef>

typedef __bf16 bf16_t;
typedef bf16_t bf16x8 __attribute__((ext_vector_type(8)));
typedef bf16_t bf16x4 __attribute__((ext_vector_type(4)));
typedef float  f32x4  __attribute__((ext_vector_type(4)));

#define TOK 16384   // B*S
#define Hh  1024    // hidden
#define F2  2048    // 2*H
#define NC  4096    // interleaved expert cols: h*4+d

__device__ __forceinline__ void gload_lds16(const bf16_t* g, bf16_t* lds) {
  __builtin_amdgcn_global_load_lds(
      (const __attribute__((address_space(1))) void*)g,
      (__attribute__((address_space(3))) void*)lds, 16, 0, 0);
}

// ---------------- x fp32 -> bf16 ----------------
__global__ void k_cvt_x(const float* __restrict__ x, bf16_t* __restrict__ o) {
  int i = blockIdx.x * blockDim.x + threadIdx.x;
  int stride = gridDim.x * blockDim.x;
  const float4* x4 = (const float4*)x;
  for (int j = i; j < TOK * Hh / 4; j += stride) {
    float4 v = x4[j];
    bf16x4 r = { (bf16_t)v.x, (bf16_t)v.y, (bf16_t)v.z, (bf16_t)v.w };
    *(bf16x4*)(o + (size_t)j * 4) = r;
  }
}

// ---- Wf [1024][2048] fp32 -> wft [2048][1024] bf16 (tiled transpose) ----
__global__ __launch_bounds__(256)
void k_tr_wf(const float* __restrict__ in, bf16_t* __restrict__ out) {
  __shared__ float T[64][65];
  const int f0 = blockIdx.x * 64, h0 = blockIdx.y * 64;
  const int tid = threadIdx.x;
  const int c4 = (tid & 15) * 4, r = tid >> 4;
  #pragma unroll
  for (int p = 0; p < 4; ++p) {
    int hh = p * 16 + r;
    float4 v = *(const float4*)&in[(size_t)(h0 + hh) * F2 + f0 + c4];
    T[c4 + 0][hh] = v.x; T[c4 + 1][hh] = v.y; T[c4 + 2][hh] = v.z; T[c4 + 3][hh] = v.w;
  }
  __syncthreads();
  #pragma unroll
  for (int p = 0; p < 4; ++p) {
    int ff = p * 16 + r;
    bf16x4 o = { (bf16_t)T[ff][c4 + 0], (bf16_t)T[ff][c4 + 1],
                 (bf16_t)T[ff][c4 + 2], (bf16_t)T[ff][c4 + 3] };
    *(bf16x4*)&out[(size_t)(f0 + ff) * Hh + h0 + c4] = o;
  }
}

// ---- We [4][2048][1024] fp32 -> wet [4096][2048] bf16, row cp = h*4+d ----
__global__ __launch_bounds__(256)
void k_tr_we(const float* __restrict__ in, bf16_t* __restrict__ out) {
  __shared__ float T[64][65];
  const int f0 = blockIdx.x * 64, h0 = blockIdx.y * 64, d = blockIdx.z;
  const float* ind = in + (size_t)d * F2 * Hh;
  const int tid = threadIdx.x;
  const int c4 = (tid & 15) * 4, r = tid >> 4;
  #pragma unroll
  for (int p = 0; p < 4; ++p) {
    int ff = p * 16 + r;
    float4 v = *(const float4*)&ind[(size_t)(f0 + ff) * Hh + h0 + c4];
    T[c4 + 0][ff] = v.x; T[c4 + 1][ff] = v.y; T[c4 + 2][ff] = v.z; T[c4 + 3][ff] = v.w;
  }
  __syncthreads();
  #pragma unroll
  for (int p = 0; p < 4; ++p) {
    int hh = p * 16 + r;
    bf16x4 o = { (bf16_t)T[hh][c4 + 0], (bf16_t)T[hh][c4 + 1],
                 (bf16_t)T[hh][c4 + 2], (bf16_t)T[hh][c4 + 3] };
    *(bf16x4*)&out[(size_t)((h0 + hh) * 4 + d) * F2 + f0 + c4] = o;
  }
}

// ---- per-token router logits ----
__global__ void k_router_t(const float* __restrict__ x, const float* __restrict__ vol,
                           const float* __restrict__ risk, const float* __restrict__ clsb,
                           const float* __restrict__ vw, const float* __restrict__ vb,
                           const float* __restrict__ rw, const float* __restrict__ rb,
                           const float* __restrict__ sw, const float* __restrict__ sb,
                           float* __restrict__ LP, int m0, int Tc) {
  int t = blockIdx.x * blockDim.x + threadIdx.x;
  if (t >= Tc) return;
  int s = m0 + t;
  const float4* xr = (const float4*)(x + (size_t)s * Hh);
  float sum = 0.f, sq = 0.f, mx = -1e30f;
  for (int i = 0; i < Hh / 4; ++i) {
    float4 v = xr[i];
    sum += v.x + v.y + v.z + v.w;
    sq  += v.x * v.x + v.y * v.y + v.z * v.z + v.w * v.w;
    mx = fmaxf(mx, fmaxf(fmaxf(v.x, v.y), fmaxf(v.z, v.w)));
  }
  float mean = sum * (1.0f / Hh);
  float var  = sq * (1.0f / Hh) - mean * mean;
  float sd   = sqrtf(fmaxf(var, 0.f));
  float v = vol[s], rk = risk[s];
  #pragma unroll
  for (int d = 0; d < 4; ++d) {
    float acc = clsb[d];
    #pragma unroll
    for (int k = 0; k < 8; ++k)  acc += tanhf(v  * vw[k*4+d] + vb[k*4+d]);
    #pragma unroll
    for (int k = 0; k < 8; ++k)  acc += tanhf(rk * rw[k*4+d] + rb[k*4+d]);
    #pragma unroll
    for (int k = 0; k < 12; ++k)
      acc += tanhf(mean * sw[k*4+d] + sd * sw[48 + k*4+d] + mx * sw[96 + k*4+d] + sb[k*4+d]);
    LP[t * 4 + d] = acc;
  }
}

// ---------------- GEMM 1 (MFMA 128^2, m97-style): feat = tanh(xbf @ wft^T + fb) ----------------
__global__ __launch_bounds__(256, 2)
void k_feat_gemm(const bf16_t* __restrict__ A,   // [Tc][1024]
                 const bf16_t* __restrict__ Bt,  // [2048][1024]
                 const float* __restrict__ bias, // [2048]
                 bf16_t* __restrict__ feat) {    // [Tc][2048]
  constexpr int K = Hh;
  __shared__ bf16_t As[128 * 64];
  __shared__ bf16_t Bs[128 * 64];
  const int bm = blockIdx.x, bn = blockIdx.y;
  const int tid = threadIdx.x;
  const int w = tid >> 6, l = tid & 63;
  const int wm = (w >> 1) * 64, wn = (w & 1) * 64;
  f32x4 acc[4][4] = {};
  for (int kk = 0; kk < K; kk += 64) {
    __syncthreads();
    #pragma unroll
    for (int c = 0; c < 4; ++c) {
      int q = (w * 4 + c) * 64 + l;
      int row = q >> 3, slot = q & 7;
      gload_lds16(A  + (size_t)(bm * 128 + row) * K + kk + slot * 8, &As[(w * 4 + c) * 512]);
      gload_lds16(Bt + (size_t)(bn * 128 + row) * K + kk + slot * 8, &Bs[(w * 4 + c) * 512]);
    }
    __syncthreads();
    #pragma unroll
    for (int ks = 0; ks < 2; ++ks) {
      bf16x8 av[4], bv[4];
      #pragma unroll
      for (int mi = 0; mi < 4; ++mi)
        av[mi] = *(const bf16x8*)&As[(wm + mi * 16 + (l & 15)) * 64 + ks * 32 + (l >> 4) * 8];
      #pragma unroll
      for (int ni = 0; ni < 4; ++ni)
        bv[ni] = *(const bf16x8*)&Bs[(wn + ni * 16 + (l & 15)) * 64 + ks * 32 + (l >> 4) * 8];
      #pragma unroll
      for (int mi = 0; mi < 4; ++mi)
        #pragma unroll
        for (int ni = 0; ni < 4; ++ni)
          acc[mi][ni] = __builtin_amdgcn_mfma_f32_16x16x32_bf16(av[mi], bv[ni], acc[mi][ni], 0, 0, 0);
    }
  }
  #pragma unroll
  for (int mi = 0; mi < 4; ++mi)
    #pragma unroll
    for (int ni = 0; ni < 4; ++ni) {
      int gn = bn * 128 + wn + ni * 16 + (l & 15);
      float bv = bias[gn];
      #pragma unroll
      for (int r = 0; r < 4; ++r) {
        int gm = bm * 128 + wm + mi * 16 + (l >> 4) * 4 + r;
        feat[(size_t)gm * F2 + gn] = (bf16_t)tanhf(acc[mi][ni][r] + bv);
      }
    }
}

// ---- dom logits + softmax (wave per token), in-place LP ----
__global__ void k_dom(const bf16_t* __restrict__ feat, const float* __restrict__ Wc,
                      float* __restrict__ LP) {
  int w = threadIdx.x >> 6, l = threadIdx.x & 63;
  int t = blockIdx.x * 4 + w;
  const bf16_t* fr = feat + (size_t)t * F2;
  const float4* Wc4 = (const float4*)Wc;
  float a0 = 0, a1 = 0, a2 = 0, a3 = 0;
  #pragma unroll
  for (int it = 0; it < 4; ++it) {
    int f0 = it * 512 + l * 8;
    bf16x8 v = *(const bf16x8*)(fr + f0);
    #pragma unroll
    for (int j = 0; j < 8; ++j) {
      float vf = (float)v[j];
      float4 wv = Wc4[f0 + j];
      a0 += vf * wv.x; a1 += vf * wv.y; a2 += vf * wv.z; a3 += vf * wv.w;
    }
  }
  #pragma unroll
  for (int off = 32; off; off >>= 1) {
    a0 += __shfl_xor(a0, off, 64); a1 += __shfl_xor(a1, off, 64);
    a2 += __shfl_xor(a2, off, 64); a3 += __shfl_xor(a3, off, 64);
  }
  if (l == 0) {
    float l0 = a0 + LP[t*4+0], l1 = a1 + LP[t*4+1];
    float l2 = a2 + LP[t*4+2], l3 = a3 + LP[t*4+3];
    float m = fmaxf(fmaxf(l0, l1), fmaxf(l2, l3));
    float e0 = expf(l0 - m), e1 = expf(l1 - m), e2 = expf(l2 - m), e3 = expf(l3 - m);
    float inv = 1.f / (e0 + e1 + e2 + e3);
    LP[t*4+0] = e0 * inv; LP[t*4+1] = e1 * inv; LP[t*4+2] = e2 * inv; LP[t*4+3] = e3 * inv;
  }
}

// ---------------- GEMM 2: 256x256, BK=32, 4-buffer, register read-ahead pipeline ----------------
// per tile t: STAGE(t+3) | ah-reads(t) | bfr/al-reads(t+1) into ALT reg set |
//             16 MFMA (zero-dep) + 16 MFMA (ah-gated) | vmcnt(4) | barrier
__global__ __launch_bounds__(512, 1)
void k_expert_gemm256(const bf16_t* __restrict__ A, const bf16_t* __restrict__ Bt,
                      const float* __restrict__ P, const float* __restrict__ EB,
                      float* __restrict__ out, int nbm) {
  constexpr int K = F2, NT = K / 32;          // 64 K-tiles of 32
  __shared__ bf16_t lds[4 * 8192 * 2];        // A: 4 bufs x [256][32]; B follows
  bf16_t* ldsB = lds + 32768;
  const int tid = threadIdx.x;
  const int l = tid & 63, wid = tid >> 6;
  const int wm = wid >> 2, wn = wid & 3;      // 2 x 4 waves
  const int l15 = l & 15, lg = l >> 4;

  // XCD-bijective block swizzle (nwg = nbm*16, multiple of 8)
  const int nwg = nbm * 16, cpx = nwg >> 3;
  int swzb = (blockIdx.x & 7) * cpx + (blockIdx.x >> 3);
  const int bm = swzb % nbm, bn = swzb / nbm;

  const bf16_t* gA = A  + (size_t)(bm * 256) * K;
  const bf16_t* gB = Bt + (size_t)(bn * 256) * K;

  // staging: slot = i*512+tid; row=slot>>2, granule=slot&3; linear LDS dest,
  // inverse-swizzled global source (granule ^ row-bits-1:2; involution)
  int s_row[2], s_gx[2];
  #pragma unroll
  for (int i = 0; i < 2; ++i) {
    int slot = i * 512 + tid;
    s_row[i] = slot >> 2;
    s_gx[i]  = ((slot & 3) ^ ((s_row[i] >> 1) & 3)) << 3;
  }

  #define STAGE(ts) do {                                                     \
    bf16_t* dstA = lds  + ((ts) & 3) * 8192;                                 \
    bf16_t* dstB = ldsB + ((ts) & 3) * 8192;                                 \
    _Pragma("unroll")                                                        \
    for (int i = 0; i < 2; ++i)                                              \
      gload_lds16(gA + (size_t)s_row[i] * K + (ts) * 32 + s_gx[i],           \
                  dstA + (i * 512 + tid) * 8);                               \
    _Pragma("unroll")                                                        \
    for (int i = 0; i < 2; ++i)                                              \
      gload_lds16(gB + (size_t)s_row[i] * K + (ts) * 32 + s_gx[i],           \
                  dstB + (i * 512 + tid) * 8);                               \
  } while (0)
  #define FENCE asm volatile("" ::: "memory")

  const int cswz = ((lg ^ ((l15 >> 1) & 3)) << 3);   // swizzled read offset in row
  f32x4 acc[8][4] = {};
  bf16x8 bfrE[4], alE[4], bfrO[4], alO[4], ah[4];

  // prologue: stage tiles 0,1,2; vmcnt(4) -> tiles 0 AND 1 landed; read set E(0)
  STAGE(0); STAGE(1); STAGE(2);
  asm volatile("s_waitcnt vmcnt(4)" ::: "memory");
  FENCE; __builtin_amdgcn_s_barrier(); FENCE;
  #pragma unroll
  for (int ni = 0; ni < 4; ++ni)
    bfrE[ni] = *(const bf16x8*)&ldsB[(wn * 64 + ni * 16 + l15) * 32 + cswz];
  #pragma unroll
  for (int mi = 0; mi < 4; ++mi)
    alE[mi] = *(const bf16x8*)&lds[(wm * 128 + mi * 16 + l15) * 32 + cswz];

  // TILE_BODY: cur set (bfrC,alC) computes tile T; next set (bfrN,alN) prefetched for T+1
  #define TILE_BODY(T, bfrC, alC, bfrN, alN, DOSTAGE, DOREADS, VMN)            \
  {                                                                            \
    const bf16_t* AsC = lds  + ((T) & 3) * 8192;                               \
    const bf16_t* BsC = ldsB + ((T) & 3) * 8192;                               \
    const bf16_t* AsN = lds  + (((T) + 1) & 3) * 8192;                         \
    const bf16_t* BsN = ldsB + (((T) + 1) & 3) * 8192;                         \
    if (DOSTAGE) STAGE((T) + 3);                                               \
    _Pragma("unroll")                                                          \
    for (int mi = 0; mi < 4; ++mi)                                             \
      ah[mi] = *(const bf16x8*)&AsC[(wm * 128 + 64 + mi * 16 + l15) * 32 + cswz]; \
    if (DOREADS) {                                                             \
      _Pragma("unroll")                                                        \
      for (int ni = 0; ni < 4; ++ni)                                           \
        bfrN[ni] = *(const bf16x8*)&BsN[(wn * 64 + ni * 16 + l15) * 32 + cswz];\
      _Pragma("unroll")                                                        \
      for (int mi = 0; mi < 4; ++mi)                                           \
        alN[mi] = *(const bf16x8*)&AsN[(wm * 128 + mi * 16 + l15) * 32 + cswz];\
    }                                                                          \
    __builtin_amdgcn_s_setprio(1);                                             \
    _Pragma("unroll")                                                          \
    for (int ni = 0; ni < 4; ++ni)                                             \
      _Pragma("unroll")                                                        \
      for (int mi = 0; mi < 4; ++mi)                                           \
        acc[mi][ni] = __builtin_amdgcn_mfma_f32_16x16x32_bf16(                 \
            alC[mi], bfrC[ni], acc[mi][ni], 0, 0, 0);                          \
    _Pragma("unroll")                                                          \
    for (int ni = 0; ni < 4; ++ni)                                             \
      _Pragma("unroll")                                                        \
      for (int mi = 0; mi < 4; ++mi)                                           \
        acc[4 + mi][ni] = __builtin_amdgcn_mfma_f32_16x16x32_bf16(             \
            ah[mi], bfrC[ni], acc[4 + mi][ni], 0, 0, 0);                       \
    __builtin_amdgcn_s_setprio(0);                                             \
    asm volatile("s_waitcnt vmcnt(" #VMN ")" ::: "memory");                    \
    FENCE; __builtin_amdgcn_s_barrier(); FENCE;                                \
  }

  // main loop: tiles 0..59, branch-free body (stage & reads always valid)
  for (int tp = 0; tp < NT - 4; tp += 2) {
    TILE_BODY(tp,     bfrE, alE, bfrO, alO, true, true, 4);
    TILE_BODY(tp + 1, bfrO, alO, bfrE, alE, true, true, 4);
  }
  // tail: tiles 60..63 peeled
  TILE_BODY(NT - 4, bfrE, alE, bfrO, alO, true,  true,  4);
  TILE_BODY(NT - 3, bfrO, alO, bfrE, alE, false, true,  0);
  TILE_BODY(NT - 2, bfrE, alE, bfrO, alO, false, true,  0);
  TILE_BODY(NT - 1, bfrO, alO, bfrE, alE, false, false, 0);
  #undef TILE_BODY
  #undef STAGE
  #undef FENCE

  // epilogue: gated combine (cols 4h..4h+3 in lane quad) -> fp32 out
  #pragma unroll
  for (int mi = 0; mi < 8; ++mi) {
    int gmBase = bm * 256 + wm * 128 + mi * 16 + lg * 4;
    float pr[4];
    #pragma unroll
    for (int r = 0; r < 4; ++r) pr[r] = P[(gmBase + r) * 4 + (l & 3)];
    #pragma unroll
    for (int ni = 0; ni < 4; ++ni) {
      int colp = bn * 256 + wn * 64 + ni * 16 + l15;
      int h = colp >> 2;
      #pragma unroll
      for (int r = 0; r < 4; ++r) {
        float sv = acc[mi][ni][r] * pr[r];
        sv += __shfl_xor(sv, 1, 64);
        sv += __shfl_xor(sv, 2, 64);
        if ((l & 3) == 0) {
          int gm = gmBase + r;
          float bt = P[gm*4+0]*EB[h] + P[gm*4+1]*EB[Hh+h]
                   + P[gm*4+2]*EB[2*Hh+h] + P[gm*4+3]*EB[3*Hh+h];
          out[(size_t)gm * Hh + h] = sv + bt;
        }
      }
    }
  }
}

extern "C" void kernel_launch(void* const* d_in, const int* in_sizes, int n_in,
                              void* d_out, int out_size, void* d_ws, size_t ws_size,
                              hipStream_t stream) {
  const float *x  = (const float*)d_in[0],  *vol = (const float*)d_in[1];
  const float *risk = (const float*)d_in[2], *Wf = (const float*)d_in[3];
  const float *fb = (const float*)d_in[4],  *Wc = (const float*)d_in[5];
  const float *cb = (const float*)d_in[6],  *vw = (const float*)d_in[7];
  const float *vb = (const float*)d_in[8],  *rw = (const float*)d_in[9];
  const float *rb = (const float*)d_in[10], *sw = (const float*)d_in[11];
  const float *sb = (const float*)d_in[12], *We = (const float*)d_in[13];
  const float *eb = (const float*)d_in[14];

  float* out = (float*)d_out;   // fp32 output
  char* ws = (char*)d_ws;
  const size_t KB = 1024, MB = 1024 * 1024;

  float*  LP  = (float*) ws;
  bf16_t* wft = (bf16_t*)(ws + 256 * KB);
  bf16_t* wet = (bf16_t*)(ws + 256 * KB + 4 * MB);
  bf16_t* xbf = (bf16_t*)(ws + 256 * KB + 20 * MB);
  const size_t base = 256 * KB + 52 * MB;
  int Tc = TOK;
  while (Tc > 1024 && base + (size_t)Tc * F2 * sizeof(bf16_t) > ws_size) Tc >>= 1;
  bf16_t* feat = (bf16_t*)(ws + base);

  k_cvt_x <<<2048, 256, 0, stream>>>(x, xbf);
  k_tr_wf <<<dim3(F2 / 64, Hh / 64), 256, 0, stream>>>(Wf, wft);
  k_tr_we <<<dim3(F2 / 64, Hh / 64, 4), 256, 0, stream>>>(We, wet);

  for (int m0 = 0; m0 < TOK; m0 += Tc) {
    k_router_t<<<(Tc + 255) / 256, 256, 0, stream>>>(
        x, vol, risk, cb, vw, vb, rw, rb, sw, sb, LP, m0, Tc);
    k_feat_gemm<<<dim3(Tc / 128, F2 / 128), 256, 0, stream>>>(
        xbf + (size_t)m0 * Hh, wft, fb, feat);
    k_dom<<<Tc / 4, 256, 0, stream>>>(feat, Wc, LP);
    int nbm = Tc / 256;
    k_expert_gemm256<<<nbm * (NC / 256), 512, 0, stream>>>(
        feat, wet, LP, eb, out + (size_t)m0 * Hh, nbm);
  }
}